// Round 3
// baseline (656.920 us; speedup 1.0000x reference)
//
#include <hip/hip_runtime.h>

constexpr int NN   = 50000;            // nodes
constexpr int NE   = 800000;           // edges (before self-loops)
constexpr int NET  = NE + NN;          // edges incl. self-loops
constexpr int NG   = 512;              // graphs
constexpr int NLAT = 64;               // latent dim
constexpr float SLOPE = 0.2f;          // leaky relu slope

__device__ __forceinline__ void edge_sd(const int* __restrict__ ei, int e, int& s_, int& d_) {
  if (e < NE) { s_ = ei[e]; d_ = ei[NE + e]; } else { s_ = d_ = e - NE; }
}

// ======================= CSR build (per launch, reused by 3 layers) =======================
__global__ void hist_kernel(const int* __restrict__ ei, int* __restrict__ deg) {
  int e = blockIdx.x * 256 + threadIdx.x;
  if (e >= NET) return;
  int s_, d_; edge_sd(ei, e, s_, d_);
  atomicAdd(&deg[d_], 1);
}

__global__ void scan_a(const int* __restrict__ deg, int* __restrict__ incl,
                       int* __restrict__ bsum) {
  __shared__ int tmp[256];
  int i = blockIdx.x * 256 + threadIdx.x;
  int v = (i < NN) ? deg[i] : 0;
  tmp[threadIdx.x] = v;
  __syncthreads();
  for (int off = 1; off < 256; off <<= 1) {
    int t = (threadIdx.x >= off) ? tmp[threadIdx.x - off] : 0;
    __syncthreads();
    tmp[threadIdx.x] += t;
    __syncthreads();
  }
  if (i < NN) incl[i] = tmp[threadIdx.x];
  if (threadIdx.x == 255) bsum[blockIdx.x] = tmp[255];
}

__global__ void scan_b(int* __restrict__ bsum, int nb) {  // single block
  __shared__ int tmp[256];
  int v = (threadIdx.x < nb) ? bsum[threadIdx.x] : 0;
  tmp[threadIdx.x] = v;
  __syncthreads();
  for (int off = 1; off < 256; off <<= 1) {
    int t = (threadIdx.x >= off) ? tmp[threadIdx.x - off] : 0;
    __syncthreads();
    tmp[threadIdx.x] += t;
    __syncthreads();
  }
  if (threadIdx.x < nb) bsum[threadIdx.x] = tmp[threadIdx.x];
}

__global__ void scan_c(const int* __restrict__ incl, const int* __restrict__ bsum,
                       const int* __restrict__ deg, int* __restrict__ row_ptr,
                       int* __restrict__ cursor) {
  int i = blockIdx.x * 256 + threadIdx.x;
  if (i >= NN) return;
  int off = blockIdx.x ? bsum[blockIdx.x - 1] : 0;
  int inc = incl[i] + off;
  row_ptr[i + 1] = inc;
  cursor[i] = inc - deg[i];
  if (i == 0) row_ptr[0] = 0;
}

__global__ void scatter_kernel(const int* __restrict__ ei, int* __restrict__ cursor,
                               int* __restrict__ ssrc) {
  int e = blockIdx.x * 256 + threadIdx.x;
  if (e >= NET) return;
  int s_, d_; edge_sd(ei, e, s_, d_);
  int pos = atomicAdd(&cursor[d_], 1);
  ssrc[pos] = s_;
}

// ======================= weight transposes (tiny) =======================
__global__ void transpose_all(const float* __restrict__ W1, const float* __restrict__ W2,
                              const float* __restrict__ W3, float* __restrict__ WT1,
                              float* __restrict__ WT2, float* __restrict__ WT3) {
  int i = blockIdx.x * 256 + threadIdx.x;
  if (i < 16384)            { int k = i >> 7, c = i & 127; WT1[c * 128 + k] = W1[i]; }
  else if (i < 32768)       { int j = i - 16384; int k = j >> 7, c = j & 127; WT2[c * 128 + k] = W2[j]; }
  else if (i < 32768 + 4096){ int j = i - 32768; int k = j >> 5, c = j & 31;  WT3[c * 128 + k] = W3[j]; }
}

// ============ GEMM (K=128) with fused attention-coefficient epilogue ============
// 256 threads; thread owns RPT rows x 8 cols. R=64 rows/block. WT is [CN][128].
template <int CN>   // 128 (H=4) or 32 (H=1)
__global__ void gemm_attn(const float* __restrict__ X, const float* __restrict__ WT,
                          const float* __restrict__ aS, const float* __restrict__ aD,
                          float* __restrict__ Hout, float* __restrict__ alS,
                          float* __restrict__ alD) {
  constexpr int CG  = CN / 8;     // col-groups (16 or 4)
  constexpr int RG  = 256 / CG;   // row-groups (16 or 64)
  constexpr int RPT = 64 / RG;    // rows per thread (4 or 1)
  constexpr int H   = CN / 32;
  __shared__ float xs[64][132];   // +4 pad: 2-way max bank aliasing (free)
  const int cg = threadIdx.x % CG;
  const int rg = threadIdx.x / CG;
  const int row0 = blockIdx.x * 64;
  // stage X rows (float4, coalesced)
  for (int i = threadIdx.x; i < 64 * 32; i += 256) {
    int r = i >> 5, k4 = i & 31;
    int gr = row0 + r;
    float4 v = (gr < NN) ? ((const float4*)X)[gr * 32 + k4] : float4{0.f, 0.f, 0.f, 0.f};
    *(float4*)&xs[r][k4 * 4] = v;
  }
  __syncthreads();
  const int col0 = cg * 8;
  float acc[RPT][8];
#pragma unroll
  for (int r = 0; r < RPT; ++r)
#pragma unroll
    for (int c = 0; c < 8; ++c) acc[r][c] = 0.f;
  const float* wp = WT + col0 * 128;
  for (int k4 = 0; k4 < 32; ++k4) {
    float4 xv[RPT];
#pragma unroll
    for (int r = 0; r < RPT; ++r) xv[r] = *(const float4*)&xs[rg * RPT + r][k4 * 4];
#pragma unroll
    for (int c = 0; c < 8; ++c) {
      float4 w = *(const float4*)&wp[c * 128 + k4 * 4];
#pragma unroll
      for (int r = 0; r < RPT; ++r) {
        acc[r][c] = fmaf(xv[r].x, w.x, acc[r][c]);
        acc[r][c] = fmaf(xv[r].y, w.y, acc[r][c]);
        acc[r][c] = fmaf(xv[r].z, w.z, acc[r][c]);
        acc[r][c] = fmaf(xv[r].w, w.w, acc[r][c]);
      }
    }
  }
  // epilogue: attention partials + H write
  float aSv[8], aDv[8];
#pragma unroll
  for (int c = 0; c < 8; ++c) { aSv[c] = aS[col0 + c]; aDv[c] = aD[col0 + c]; }
#pragma unroll
  for (int r = 0; r < RPT; ++r) {
    float ps = 0.f, pd = 0.f;
#pragma unroll
    for (int c = 0; c < 8; ++c) { ps = fmaf(acc[r][c], aSv[c], ps); pd = fmaf(acc[r][c], aDv[c], pd); }
    ps += __shfl_xor(ps, 1, 64); ps += __shfl_xor(ps, 2, 64);   // reduce 4 col-groups (one head)
    pd += __shfl_xor(pd, 1, 64); pd += __shfl_xor(pd, 2, 64);
    int row = row0 + rg * RPT + r;
    if (row < NN) {
      if ((cg & 3) == 0) {
        alS[row * H + (cg >> 2)] = ps;
        alD[row * H + (cg >> 2)] = pd;
      }
      float4 o0{acc[r][0], acc[r][1], acc[r][2], acc[r][3]};
      float4 o1{acc[r][4], acc[r][5], acc[r][6], acc[r][7]};
      *(float4*)&Hout[row * CN + col0]     = o0;
      *(float4*)&Hout[row * CN + col0 + 4] = o1;
    }
  }
}

// ============ fused softmax + aggregation, H=4: one wave/node, single edge sweep ============
// No max-subtraction: logits are O(+-10) with this data scale; exp() safe in f32.
__global__ void gat_agg_h4(const int* __restrict__ rp, const int* __restrict__ ssrc,
                           const float* __restrict__ Hf, const float* __restrict__ alS,
                           const float* __restrict__ alD, const float* __restrict__ bias,
                           float* __restrict__ outf) {
  int node = (blockIdx.x * 256 + threadIdx.x) >> 6;
  int lane = threadIdx.x & 63;
  if (node >= NN) return;
  int beg = rp[node], end = rp[node + 1];
  int el = lane & 15, hh = lane >> 4;       // stats mapping: (edge slot el, head hh)
  float ad_h = alD[node * 4 + hh];
  int h0 = lane >> 5;                       // head of channel lane (acc0); acc1 head = h0+2
  float acc0 = 0.f, acc1 = 0.f, sm = 0.f;
  for (int ch = beg; ch < end; ch += 16) {
    int cnt = min(16, end - ch);
    int sv = 0; float ev = 0.f;
    if (el < cnt) {
      sv = ssrc[ch + el];
      float x = alS[sv * 4 + hh] + ad_h;
      x = x > 0.f ? x : SLOPE * x;
      ev = __expf(x);
      sm += ev;
    }
    for (int e2 = 0; e2 < cnt; ++e2) {
      int   s  = __shfl(sv, e2, 64);
      float a0 = __shfl(ev, h0 * 16 + e2, 64);
      float a1 = __shfl(ev, (h0 + 2) * 16 + e2, 64);
      acc0 = fmaf(Hf[s * 128 + lane],      a0, acc0);
      acc1 = fmaf(Hf[s * 128 + 64 + lane], a1, acc1);
    }
  }
#pragma unroll
  for (int off = 8; off >= 1; off >>= 1) sm += __shfl_xor(sm, off, 64);  // per-head totals
  float s0 = __shfl(sm, h0 * 16, 64);
  float s1 = __shfl(sm, (h0 + 2) * 16, 64);
  float v0 = acc0 / s0 + bias[lane];
  float v1 = acc1 / s1 + bias[64 + lane];
  outf[node * 128 + lane]      = v0 > 0.f ? v0 : expm1f(v0);
  outf[node * 128 + 64 + lane] = v1 > 0.f ? v1 : expm1f(v1);
}

// ============ fused softmax + aggregation, H=1: half-wave per node ============
__global__ void gat_agg_h1(const int* __restrict__ rp, const int* __restrict__ ssrc,
                           const float* __restrict__ Hf, const float* __restrict__ alS,
                           const float* __restrict__ alD, const float* __restrict__ bias,
                           float* __restrict__ outf) {
  int node = (blockIdx.x * 256 + threadIdx.x) >> 5;
  int lane = threadIdx.x & 31;
  if (node >= NN) return;
  int beg = rp[node], end = rp[node + 1];
  float ad = alD[node];
  float acc = 0.f, sm = 0.f;
  for (int ch = beg; ch < end; ch += 32) {
    int cnt = min(32, end - ch);
    int sv = 0; float ev = 0.f;
    if (lane < cnt) {
      sv = ssrc[ch + lane];
      float x = alS[sv] + ad;
      x = x > 0.f ? x : SLOPE * x;
      ev = __expf(x);
      sm += ev;
    }
    for (int e2 = 0; e2 < cnt; ++e2) {
      int   s = __shfl(sv, e2, 32);
      float a = __shfl(ev, e2, 32);
      acc = fmaf(Hf[s * 32 + lane], a, acc);
    }
  }
#pragma unroll
  for (int off = 16; off >= 1; off >>= 1) sm += __shfl_xor(sm, off, 32);
  float v = acc / sm + bias[lane];
  outf[node * 32 + lane] = v > 0.f ? v : expm1f(v);
}

// ======================= pool (sorted batch -> no atomics) + heads =======================
__device__ __forceinline__ int lb_batch(const int* __restrict__ b, int val) {
  int lo = 0, hi = NN;
  while (lo < hi) { int mid = (lo + hi) >> 1; if (b[mid] < val) lo = mid + 1; else hi = mid; }
  return lo;
}

__global__ void pool_kernel(const float* __restrict__ feat, const int* __restrict__ batch,
                            float* __restrict__ pooled) {
  int g = blockIdx.x;
  int start = lb_batch(batch, g), end = lb_batch(batch, g + 1);
  int c = threadIdx.x & 31, sub = threadIdx.x >> 5;
  float acc = 0.f;
  for (int n = start + sub; n < end; n += 8) acc += feat[n * 32 + c];
  __shared__ float red[8][32];
  red[sub][c] = acc;
  __syncthreads();
  if (threadIdx.x < 32) {
    float s = 0.f;
#pragma unroll
    for (int i = 0; i < 8; ++i) s += red[i][c];
    pooled[g * 32 + c] = s / fmaxf((float)(end - start), 1.0f);
  }
}

__global__ void head_kernel(const float* __restrict__ pooled,
                            const float* __restrict__ Wmu, const float* __restrict__ bmu,
                            const float* __restrict__ Wlv, const float* __restrict__ blv,
                            float* __restrict__ out) {
  int idx = blockIdx.x * 256 + threadIdx.x;
  if (idx >= NG * NLAT) return;
  int g = idx / NLAT, l = idx % NLAT;
  float mu = bmu[l], lv = blv[l];
#pragma unroll
  for (int k = 0; k < 32; ++k) {
    float p = pooled[g * 32 + k];
    mu = fmaf(p, Wmu[k * NLAT + l], mu);
    lv = fmaf(p, Wlv[k * NLAT + l], lv);
  }
  out[g * NLAT + l] = mu;
  out[NG * NLAT + g * NLAT + l] = lv;
}

extern "C" void kernel_launch(void* const* d_in, const int* in_sizes, int n_in,
                              void* d_out, int out_size, void* d_ws, size_t ws_size,
                              hipStream_t stream) {
  const float* x     = (const float*)d_in[0];
  const float* W1    = (const float*)d_in[1];
  const float* as1   = (const float*)d_in[2];
  const float* ad1   = (const float*)d_in[3];
  const float* b1    = (const float*)d_in[4];
  const float* W2    = (const float*)d_in[5];
  const float* as2   = (const float*)d_in[6];
  const float* ad2   = (const float*)d_in[7];
  const float* b2    = (const float*)d_in[8];
  const float* W3    = (const float*)d_in[9];
  const float* as3   = (const float*)d_in[10];
  const float* ad3   = (const float*)d_in[11];
  const float* b3    = (const float*)d_in[12];
  const float* Wmu   = (const float*)d_in[13];
  const float* bmu   = (const float*)d_in[14];
  const float* Wlv   = (const float*)d_in[15];
  const float* blv   = (const float*)d_in[16];
  const int*   ei    = (const int*)d_in[17];
  const int*   batch = (const int*)d_in[18];
  float* out = (float*)d_out;

  float* ws    = (float*)d_ws;
  float* A     = ws;                          // [N,128] GEMM output (h)
  float* B     = A + (size_t)NN * 128;        // [N,128] agg/feature buffer
  float* alS   = B + (size_t)NN * 128;        // [N,4]
  float* alD   = alS + (size_t)NN * 4;        // [N,4]
  float* pooled= alD + (size_t)NN * 4;        // [G,32]
  float* wt1   = pooled + (size_t)NG * 32;    // [128*128]
  float* wt2   = wt1 + 16384;                 // [128*128]
  float* wt3   = wt2 + 16384;                 // [32*128]
  int* deg     = (int*)(wt3 + 4096);          // [N]
  int* rp      = deg + NN;                    // [N+1]
  int* cursor  = rp + NN + 1;                 // [N]
  int* incl    = cursor + NN;                 // [N]
  int* bsum    = incl + NN;                   // [256]
  int* ssrc    = bsum + 256;                  // [NET]

  dim3 blk(256);
  const int EG  = (NET + 255) / 256;
  const int SCB = (NN + 255) / 256;
  const int GB  = (NN + 63) / 64;             // gemm blocks

  // ---------------- CSR build + weight transposes ----------------
  hipMemsetAsync(deg, 0, (size_t)NN * sizeof(int), stream);
  hist_kernel<<<EG, blk, 0, stream>>>(ei, deg);
  scan_a<<<SCB, blk, 0, stream>>>(deg, incl, bsum);
  scan_b<<<1, blk, 0, stream>>>(bsum, SCB);
  scan_c<<<SCB, blk, 0, stream>>>(incl, bsum, deg, rp, cursor);
  scatter_kernel<<<EG, blk, 0, stream>>>(ei, cursor, ssrc);
  transpose_all<<<144, blk, 0, stream>>>(W1, W2, W3, wt1, wt2, wt3);

  // ---------------- layer 1 ----------------
  gemm_attn<128><<<GB, blk, 0, stream>>>(x, wt1, as1, ad1, A, alS, alD);
  gat_agg_h4<<<(NN * 64) / 256, blk, 0, stream>>>(rp, ssrc, A, alS, alD, b1, B);
  // ---------------- layer 2 ----------------
  gemm_attn<128><<<GB, blk, 0, stream>>>(B, wt2, as2, ad2, A, alS, alD);
  gat_agg_h4<<<(NN * 64) / 256, blk, 0, stream>>>(rp, ssrc, A, alS, alD, b2, B);
  // ---------------- layer 3 ----------------
  gemm_attn<32><<<GB, blk, 0, stream>>>(B, wt3, as3, ad3, A, alS, alD);
  gat_agg_h1<<<(NN * 32) / 256, blk, 0, stream>>>(rp, ssrc, A, alS, alD, b3, B);

  // ---------------- pool + heads ----------------
  pool_kernel<<<NG, blk, 0, stream>>>(B, batch, pooled);
  head_kernel<<<(NG * NLAT + 255) / 256, blk, 0, stream>>>(pooled, Wmu, bmu, Wlv, blv, out);
}

// Round 4
// 377.297 us; speedup vs baseline: 1.7411x; 1.7411x over previous
//
#include <hip/hip_runtime.h>

constexpr int NN   = 50000;            // nodes
constexpr int NE   = 800000;           // edges (before self-loops)
constexpr int NET  = NE + NN;          // edges incl. self-loops
constexpr int NG   = 512;              // graphs
constexpr int NLAT = 64;               // latent dim
constexpr float SLOPE = 0.2f;          // leaky relu slope

__device__ __forceinline__ void edge_sd(const int* __restrict__ ei, int e, int& s_, int& d_) {
  if (e < NE) { s_ = ei[e]; d_ = ei[NE + e]; } else { s_ = d_ = e - NE; }
}

// ======================= CSR build (per launch, reused by 3 layers) =======================
__global__ void hist_kernel(const int* __restrict__ ei, int* __restrict__ deg) {
  int e = blockIdx.x * 256 + threadIdx.x;
  if (e >= NET) return;
  int s_, d_; edge_sd(ei, e, s_, d_);
  atomicAdd(&deg[d_], 1);
}

__global__ void scan_a(const int* __restrict__ deg, int* __restrict__ incl,
                       int* __restrict__ bsum) {
  __shared__ int tmp[256];
  int i = blockIdx.x * 256 + threadIdx.x;
  int v = (i < NN) ? deg[i] : 0;
  tmp[threadIdx.x] = v;
  __syncthreads();
  for (int off = 1; off < 256; off <<= 1) {
    int t = (threadIdx.x >= off) ? tmp[threadIdx.x - off] : 0;
    __syncthreads();
    tmp[threadIdx.x] += t;
    __syncthreads();
  }
  if (i < NN) incl[i] = tmp[threadIdx.x];
  if (threadIdx.x == 255) bsum[blockIdx.x] = tmp[255];
}

__global__ void scan_b(int* __restrict__ bsum, int nb) {  // single block
  __shared__ int tmp[256];
  int v = (threadIdx.x < nb) ? bsum[threadIdx.x] : 0;
  tmp[threadIdx.x] = v;
  __syncthreads();
  for (int off = 1; off < 256; off <<= 1) {
    int t = (threadIdx.x >= off) ? tmp[threadIdx.x - off] : 0;
    __syncthreads();
    tmp[threadIdx.x] += t;
    __syncthreads();
  }
  if (threadIdx.x < nb) bsum[threadIdx.x] = tmp[threadIdx.x];
}

__global__ void scan_c(const int* __restrict__ incl, const int* __restrict__ bsum,
                       const int* __restrict__ deg, int* __restrict__ row_ptr,
                       int* __restrict__ cursor) {
  int i = blockIdx.x * 256 + threadIdx.x;
  if (i >= NN) return;
  int off = blockIdx.x ? bsum[blockIdx.x - 1] : 0;
  int inc = incl[i] + off;
  row_ptr[i + 1] = inc;
  cursor[i] = inc - deg[i];
  if (i == 0) row_ptr[0] = 0;
}

__global__ void scatter_kernel(const int* __restrict__ ei, int* __restrict__ cursor,
                               int* __restrict__ ssrc) {
  int e = blockIdx.x * 256 + threadIdx.x;
  if (e >= NET) return;
  int s_, d_; edge_sd(ei, e, s_, d_);
  int pos = atomicAdd(&cursor[d_], 1);
  ssrc[pos] = s_;
}

// ============ tiled GEMM: C[n,j] = sum_k X[n,k] W[k,j]; K=128, BM=64 rows/block ============
// Both operands staged in LDS, K-chunks of 32. W consumed in native [k][col] layout.
// xs[k][row] pad 68 (2-way max on reads); ws[k][col] pad +4 (reads conflict-free/4-distinct).
template <int CN>   // 128 or 32
__global__ void gemm_tile(const float* __restrict__ X, const float* __restrict__ W,
                          float* __restrict__ Hout) {
  constexpr int CG  = CN / 8;       // col-groups: 16 or 4
  constexpr int RG  = 256 / CG;     // row-groups: 16 or 64
  constexpr int RPT = 64 / RG;      // rows/thread: 4 or 1
  __shared__ float xs[32][68];      // [k][row]
  __shared__ float ws[32][CN + 4];  // [k][col]
  const int rg = threadIdx.x % RG;
  const int cg = threadIdx.x / RG;
  const int row0 = blockIdx.x * 64;
  const int c0 = cg * 8;
  float acc[RPT][8];
#pragma unroll
  for (int r = 0; r < RPT; ++r)
#pragma unroll
    for (int c = 0; c < 8; ++c) acc[r][c] = 0.f;

  for (int chunk = 0; chunk < 4; ++chunk) {
    // stage X: 64 rows x 32 k  (scatter-transpose to [k][row])
#pragma unroll
    for (int j = 0; j < 2; ++j) {
      int idx = threadIdx.x + j * 256;
      int r = idx >> 3, s = idx & 7;
      int gr = row0 + r;
      float4 v = (gr < NN) ? *(const float4*)(X + (size_t)gr * 128 + chunk * 32 + s * 4)
                           : float4{0.f, 0.f, 0.f, 0.f};
      xs[s * 4 + 0][r] = v.x;
      xs[s * 4 + 1][r] = v.y;
      xs[s * 4 + 2][r] = v.z;
      xs[s * 4 + 3][r] = v.w;
    }
    // stage W: 32 k x CN cols (native layout, coalesced)
#pragma unroll
    for (int j = 0; j < 32 * CN / 1024; ++j) {
      int idx = threadIdx.x + j * 256;
      int k = idx / (CN / 4), s = idx % (CN / 4);
      *(float4*)&ws[k][s * 4] =
          *(const float4*)(W + (size_t)(chunk * 32 + k) * CN + s * 4);
    }
    __syncthreads();
#pragma unroll 4
    for (int k = 0; k < 32; ++k) {
      float4 w0 = *(const float4*)&ws[k][c0];
      float4 w1 = *(const float4*)&ws[k][c0 + 4];
      if constexpr (RPT == 4) {
        float4 xa = *(const float4*)&xs[k][rg * 4];
        float xv[4] = {xa.x, xa.y, xa.z, xa.w};
#pragma unroll
        for (int r = 0; r < 4; ++r) {
          acc[r][0] = fmaf(xv[r], w0.x, acc[r][0]);
          acc[r][1] = fmaf(xv[r], w0.y, acc[r][1]);
          acc[r][2] = fmaf(xv[r], w0.z, acc[r][2]);
          acc[r][3] = fmaf(xv[r], w0.w, acc[r][3]);
          acc[r][4] = fmaf(xv[r], w1.x, acc[r][4]);
          acc[r][5] = fmaf(xv[r], w1.y, acc[r][5]);
          acc[r][6] = fmaf(xv[r], w1.z, acc[r][6]);
          acc[r][7] = fmaf(xv[r], w1.w, acc[r][7]);
        }
      } else {
        float xv = xs[k][rg];
        acc[0][0] = fmaf(xv, w0.x, acc[0][0]);
        acc[0][1] = fmaf(xv, w0.y, acc[0][1]);
        acc[0][2] = fmaf(xv, w0.z, acc[0][2]);
        acc[0][3] = fmaf(xv, w0.w, acc[0][3]);
        acc[0][4] = fmaf(xv, w1.x, acc[0][4]);
        acc[0][5] = fmaf(xv, w1.y, acc[0][5]);
        acc[0][6] = fmaf(xv, w1.z, acc[0][6]);
        acc[0][7] = fmaf(xv, w1.w, acc[0][7]);
      }
    }
    __syncthreads();
  }
#pragma unroll
  for (int r = 0; r < RPT; ++r) {
    int row = row0 + rg * RPT + r;
    if (row < NN) {
      *(float4*)&Hout[(size_t)row * CN + c0]     = float4{acc[r][0], acc[r][1], acc[r][2], acc[r][3]};
      *(float4*)&Hout[(size_t)row * CN + c0 + 4] = float4{acc[r][4], acc[r][5], acc[r][6], acc[r][7]};
    }
  }
}

// ======================= per-node attention coefficients =======================
template <int F>
__global__ void attn_coef(const float* __restrict__ Hf, const float* __restrict__ a_s,
                          const float* __restrict__ a_d, float* __restrict__ al_s,
                          float* __restrict__ al_d) {
  const int t = threadIdx.x % F;
  const int node = blockIdx.x * (256 / F) + threadIdx.x / F;
  if (node >= NN) return;
  float v  = Hf[node * F + t];
  float ps = v * a_s[t];
  float pd = v * a_d[t];
#pragma unroll
  for (int off = 16; off >= 1; off >>= 1) {
    ps += __shfl_xor(ps, off, 64);
    pd += __shfl_xor(pd, off, 64);
  }
  if ((t & 31) == 0) {
    al_s[node * (F / 32) + (t >> 5)] = ps;
    al_d[node * (F / 32) + (t >> 5)] = pd;
  }
}

// ============ fused softmax + aggregation, H=4: one wave/node, batched gathers ============
// No max-subtraction: logits are O(+-10) at this data scale; exp() safe in f32.
__global__ void gat_agg_h4(const int* __restrict__ rp, const int* __restrict__ ssrc,
                           const float* __restrict__ Hf, const float* __restrict__ alS,
                           const float* __restrict__ alD, const float* __restrict__ bias,
                           float* __restrict__ outf) {
  int node = (blockIdx.x * 256 + threadIdx.x) >> 6;
  int lane = threadIdx.x & 63;
  if (node >= NN) return;
  int beg = rp[node], end = rp[node + 1];
  int el = lane & 15, hh = lane >> 4;       // alpha-phase mapping: (edge slot el, head hh)
  float ad_h = alD[node * 4 + hh];
  int h0 = lane >> 5;                       // head of channel `lane` (acc0); acc1 head = h0+2
  float acc0 = 0.f, acc1 = 0.f, sm = 0.f;
  for (int ch = beg; ch < end; ch += 16) {
    int cnt = end - ch;                     // >=1; clamp at 16 via predication
    int sv = node;                          // safe gather index for idle slots
    float ev = 0.f;
    if (el < cnt) {
      sv = ssrc[ch + el];
      float x = alS[sv * 4 + hh] + ad_h;
      x = x > 0.f ? x : SLOPE * x;
      ev = __expf(x);
      sm += ev;
    }
    int   sarr[16];
    float a0[16], a1[16];
#pragma unroll
    for (int e = 0; e < 16; ++e) {
      sarr[e] = __shfl(sv, e, 64);                      // lane e = (el=e, hh=0)
      a0[e]   = __shfl(ev, h0 * 16 + e, 64);
      a1[e]   = __shfl(ev, (h0 + 2) * 16 + e, 64);
    }
    float f0[16], f1[16];
#pragma unroll
    for (int e = 0; e < 16; ++e) {                      // 32 independent gathers in flight
      f0[e] = Hf[(size_t)sarr[e] * 128 + lane];
      f1[e] = Hf[(size_t)sarr[e] * 128 + 64 + lane];
    }
#pragma unroll
    for (int e = 0; e < 16; ++e) {
      acc0 = fmaf(f0[e], a0[e], acc0);
      acc1 = fmaf(f1[e], a1[e], acc1);
    }
  }
#pragma unroll
  for (int off = 8; off >= 1; off >>= 1) sm += __shfl_xor(sm, off, 64);  // per-16-lane head sums
  float s0 = __shfl(sm, h0 * 16, 64);
  float s1 = __shfl(sm, (h0 + 2) * 16, 64);
  float v0 = acc0 / s0 + bias[lane];
  float v1 = acc1 / s1 + bias[64 + lane];
  outf[(size_t)node * 128 + lane]      = v0 > 0.f ? v0 : expm1f(v0);
  outf[(size_t)node * 128 + 64 + lane] = v1 > 0.f ? v1 : expm1f(v1);
}

// ============ fused softmax + aggregation, H=1: half-wave/node, batched gathers ============
__global__ void gat_agg_h1(const int* __restrict__ rp, const int* __restrict__ ssrc,
                           const float* __restrict__ Hf, const float* __restrict__ alS,
                           const float* __restrict__ alD, const float* __restrict__ bias,
                           float* __restrict__ outf) {
  int node = (blockIdx.x * 256 + threadIdx.x) >> 5;
  int lane = threadIdx.x & 31;
  if (node >= NN) return;
  int beg = rp[node], end = rp[node + 1];
  float ad = alD[node];
  float acc = 0.f, sm = 0.f;
  for (int ch = beg; ch < end; ch += 16) {
    int cnt = end - ch;
    int sv = node; float ev = 0.f;
    if (lane < 16 && lane < cnt) {
      sv = ssrc[ch + lane];
      float x = alS[sv] + ad;
      x = x > 0.f ? x : SLOPE * x;
      ev = __expf(x);
      sm += ev;
    }
    int sarr[16]; float av[16];
#pragma unroll
    for (int e = 0; e < 16; ++e) {
      sarr[e] = __shfl(sv, e, 32);
      av[e]   = __shfl(ev, e, 32);
    }
    float fv[16];
#pragma unroll
    for (int e = 0; e < 16; ++e) fv[e] = Hf[(size_t)sarr[e] * 32 + lane];
#pragma unroll
    for (int e = 0; e < 16; ++e) acc = fmaf(fv[e], av[e], acc);
  }
#pragma unroll
  for (int off = 16; off >= 1; off >>= 1) sm += __shfl_xor(sm, off, 32);
  float v = acc / sm + bias[lane];
  outf[(size_t)node * 32 + lane] = v > 0.f ? v : expm1f(v);
}

// ======================= pool (sorted batch -> no atomics) + heads =======================
__device__ __forceinline__ int lb_batch(const int* __restrict__ b, int val) {
  int lo = 0, hi = NN;
  while (lo < hi) { int mid = (lo + hi) >> 1; if (b[mid] < val) lo = mid + 1; else hi = mid; }
  return lo;
}

__global__ void pool_kernel(const float* __restrict__ feat, const int* __restrict__ batch,
                            float* __restrict__ pooled) {
  int g = blockIdx.x;
  int start = lb_batch(batch, g), end = lb_batch(batch, g + 1);
  int c = threadIdx.x & 31, sub = threadIdx.x >> 5;
  float acc = 0.f;
  for (int n = start + sub; n < end; n += 8) acc += feat[(size_t)n * 32 + c];
  __shared__ float red[8][32];
  red[sub][c] = acc;
  __syncthreads();
  if (threadIdx.x < 32) {
    float s = 0.f;
#pragma unroll
    for (int i = 0; i < 8; ++i) s += red[i][c];
    pooled[g * 32 + c] = s / fmaxf((float)(end - start), 1.0f);
  }
}

__global__ void head_kernel(const float* __restrict__ pooled,
                            const float* __restrict__ Wmu, const float* __restrict__ bmu,
                            const float* __restrict__ Wlv, const float* __restrict__ blv,
                            float* __restrict__ out) {
  int idx = blockIdx.x * 256 + threadIdx.x;
  if (idx >= NG * NLAT) return;
  int g = idx / NLAT, l = idx % NLAT;
  float mu = bmu[l], lv = blv[l];
#pragma unroll
  for (int k = 0; k < 32; ++k) {
    float p = pooled[g * 32 + k];
    mu = fmaf(p, Wmu[k * NLAT + l], mu);
    lv = fmaf(p, Wlv[k * NLAT + l], lv);
  }
  out[g * NLAT + l] = mu;
  out[NG * NLAT + g * NLAT + l] = lv;
}

extern "C" void kernel_launch(void* const* d_in, const int* in_sizes, int n_in,
                              void* d_out, int out_size, void* d_ws, size_t ws_size,
                              hipStream_t stream) {
  const float* x     = (const float*)d_in[0];
  const float* W1    = (const float*)d_in[1];
  const float* as1   = (const float*)d_in[2];
  const float* ad1   = (const float*)d_in[3];
  const float* b1    = (const float*)d_in[4];
  const float* W2    = (const float*)d_in[5];
  const float* as2   = (const float*)d_in[6];
  const float* ad2   = (const float*)d_in[7];
  const float* b2    = (const float*)d_in[8];
  const float* W3    = (const float*)d_in[9];
  const float* as3   = (const float*)d_in[10];
  const float* ad3   = (const float*)d_in[11];
  const float* b3    = (const float*)d_in[12];
  const float* Wmu   = (const float*)d_in[13];
  const float* bmu   = (const float*)d_in[14];
  const float* Wlv   = (const float*)d_in[15];
  const float* blv   = (const float*)d_in[16];
  const int*   ei    = (const int*)d_in[17];
  const int*   batch = (const int*)d_in[18];
  float* out = (float*)d_out;

  float* ws    = (float*)d_ws;
  float* A     = ws;                          // [N,128] GEMM output (h)
  float* B     = A + (size_t)NN * 128;        // [N,128] agg/feature buffer
  float* alS   = B + (size_t)NN * 128;        // [N,4]
  float* alD   = alS + (size_t)NN * 4;        // [N,4]
  float* pooled= alD + (size_t)NN * 4;        // [G,32]
  int* deg     = (int*)(pooled + (size_t)NG * 32);  // [N]
  int* rp      = deg + NN;                    // [N+1]
  int* cursor  = rp + NN + 1;                 // [N]
  int* incl    = cursor + NN;                 // [N]
  int* bsum    = incl + NN;                   // [256]
  int* ssrc    = bsum + 256;                  // [NET]

  dim3 blk(256);
  const int EG  = (NET + 255) / 256;
  const int SCB = (NN + 255) / 256;
  const int GB  = (NN + 63) / 64;             // 782 gemm blocks

  // ---------------- CSR build ----------------
  hipMemsetAsync(deg, 0, (size_t)NN * sizeof(int), stream);
  hist_kernel<<<EG, blk, 0, stream>>>(ei, deg);
  scan_a<<<SCB, blk, 0, stream>>>(deg, incl, bsum);
  scan_b<<<1, blk, 0, stream>>>(bsum, SCB);
  scan_c<<<SCB, blk, 0, stream>>>(incl, bsum, deg, rp, cursor);
  scatter_kernel<<<EG, blk, 0, stream>>>(ei, cursor, ssrc);

  // ---------------- layer 1 ----------------
  gemm_tile<128><<<GB, blk, 0, stream>>>(x, W1, A);
  attn_coef<128><<<NN / 2, blk, 0, stream>>>(A, as1, ad1, alS, alD);
  gat_agg_h4<<<(NN * 64) / 256, blk, 0, stream>>>(rp, ssrc, A, alS, alD, b1, B);
  // ---------------- layer 2 ----------------
  gemm_tile<128><<<GB, blk, 0, stream>>>(B, W2, A);
  attn_coef<128><<<NN / 2, blk, 0, stream>>>(A, as2, ad2, alS, alD);
  gat_agg_h4<<<(NN * 64) / 256, blk, 0, stream>>>(rp, ssrc, A, alS, alD, b2, B);
  // ---------------- layer 3 ----------------
  gemm_tile<32><<<GB, blk, 0, stream>>>(B, W3, A);      // A as [N,32]
  attn_coef<32><<<NN / 8, blk, 0, stream>>>(A, as3, ad3, alS, alD);
  gat_agg_h1<<<(NN * 32) / 256, blk, 0, stream>>>(rp, ssrc, A, alS, alD, b3, B);

  // ---------------- pool + heads ----------------
  pool_kernel<<<NG, blk, 0, stream>>>(B, batch, pooled);
  head_kernel<<<(NG * NLAT + 255) / 256, blk, 0, stream>>>(pooled, Wmu, bmu, Wlv, blv, out);
}

// Round 5
// 304.147 us; speedup vs baseline: 2.1599x; 1.2405x over previous
//
#include <hip/hip_runtime.h>
#include <hip/hip_fp16.h>

constexpr int NN   = 50000;            // nodes
constexpr int NE   = 800000;           // edges (before self-loops)
constexpr int NET  = NE + NN;          // edges incl. self-loops
constexpr int NG   = 512;              // graphs
constexpr int NLAT = 64;               // latent dim
constexpr float SLOPE = 0.2f;          // leaky relu slope

__device__ __forceinline__ void edge_sd(const int* __restrict__ ei, int e, int& s_, int& d_) {
  if (e < NE) { s_ = ei[e]; d_ = ei[NE + e]; } else { s_ = d_ = e - NE; }
}

// ======================= CSR build (per launch, reused by 3 layers) =======================
__global__ void hist_kernel(const int* __restrict__ ei, int* __restrict__ deg) {
  int e = blockIdx.x * 256 + threadIdx.x;
  if (e >= NET) return;
  int s_, d_; edge_sd(ei, e, s_, d_);
  atomicAdd(&deg[d_], 1);
}

__global__ void scan_a(const int* __restrict__ deg, int* __restrict__ incl,
                       int* __restrict__ bsum) {
  __shared__ int tmp[256];
  int i = blockIdx.x * 256 + threadIdx.x;
  int v = (i < NN) ? deg[i] : 0;
  tmp[threadIdx.x] = v;
  __syncthreads();
  for (int off = 1; off < 256; off <<= 1) {
    int t = (threadIdx.x >= off) ? tmp[threadIdx.x - off] : 0;
    __syncthreads();
    tmp[threadIdx.x] += t;
    __syncthreads();
  }
  if (i < NN) incl[i] = tmp[threadIdx.x];
  if (threadIdx.x == 255) bsum[blockIdx.x] = tmp[255];
}

__global__ void scan_b(int* __restrict__ bsum, int nb) {  // single block
  __shared__ int tmp[256];
  int v = (threadIdx.x < nb) ? bsum[threadIdx.x] : 0;
  tmp[threadIdx.x] = v;
  __syncthreads();
  for (int off = 1; off < 256; off <<= 1) {
    int t = (threadIdx.x >= off) ? tmp[threadIdx.x - off] : 0;
    __syncthreads();
    tmp[threadIdx.x] += t;
    __syncthreads();
  }
  if (threadIdx.x < nb) bsum[threadIdx.x] = tmp[threadIdx.x];
}

__global__ void scan_c(const int* __restrict__ incl, const int* __restrict__ bsum,
                       const int* __restrict__ deg, int* __restrict__ row_ptr,
                       int* __restrict__ cursor) {
  int i = blockIdx.x * 256 + threadIdx.x;
  if (i >= NN) return;
  int off = blockIdx.x ? bsum[blockIdx.x - 1] : 0;
  int inc = incl[i] + off;
  row_ptr[i + 1] = inc;
  cursor[i] = inc - deg[i];
  if (i == 0) row_ptr[0] = 0;
}

__global__ void scatter_kernel(const int* __restrict__ ei, int* __restrict__ cursor,
                               int* __restrict__ ssrc) {
  int e = blockIdx.x * 256 + threadIdx.x;
  if (e >= NET) return;
  int s_, d_; edge_sd(ei, e, s_, d_);
  int pos = atomicAdd(&cursor[d_], 1);
  ssrc[pos] = s_;
}

// ============ tiled GEMM: C[n,j] = sum_k X[n,k] W[k,j]; K=128, BM=64; fp16 output ============
template <int CN>   // 128 or 32
__global__ void gemm_tile(const float* __restrict__ X, const float* __restrict__ W,
                          __half* __restrict__ Hout) {
  constexpr int CG  = CN / 8;       // col-groups: 16 or 4
  constexpr int RG  = 256 / CG;     // row-groups: 16 or 64
  constexpr int RPT = 64 / RG;      // rows/thread: 4 or 1
  __shared__ float xs[32][68];      // [k][row]
  __shared__ float ws[32][CN + 4];  // [k][col]
  const int rg = threadIdx.x % RG;
  const int cg = threadIdx.x / RG;
  const int row0 = blockIdx.x * 64;
  const int c0 = cg * 8;
  float acc[RPT][8];
#pragma unroll
  for (int r = 0; r < RPT; ++r)
#pragma unroll
    for (int c = 0; c < 8; ++c) acc[r][c] = 0.f;

  for (int chunk = 0; chunk < 4; ++chunk) {
#pragma unroll
    for (int j = 0; j < 2; ++j) {
      int idx = threadIdx.x + j * 256;
      int r = idx >> 3, s = idx & 7;
      int gr = row0 + r;
      float4 v = (gr < NN) ? *(const float4*)(X + (size_t)gr * 128 + chunk * 32 + s * 4)
                           : float4{0.f, 0.f, 0.f, 0.f};
      xs[s * 4 + 0][r] = v.x;
      xs[s * 4 + 1][r] = v.y;
      xs[s * 4 + 2][r] = v.z;
      xs[s * 4 + 3][r] = v.w;
    }
#pragma unroll
    for (int j = 0; j < 32 * CN / 1024; ++j) {
      int idx = threadIdx.x + j * 256;
      int k = idx / (CN / 4), s = idx % (CN / 4);
      *(float4*)&ws[k][s * 4] =
          *(const float4*)(W + (size_t)(chunk * 32 + k) * CN + s * 4);
    }
    __syncthreads();
#pragma unroll 4
    for (int k = 0; k < 32; ++k) {
      float4 w0 = *(const float4*)&ws[k][c0];
      float4 w1 = *(const float4*)&ws[k][c0 + 4];
      if constexpr (RPT == 4) {
        float4 xa = *(const float4*)&xs[k][rg * 4];
        float xv[4] = {xa.x, xa.y, xa.z, xa.w};
#pragma unroll
        for (int r = 0; r < 4; ++r) {
          acc[r][0] = fmaf(xv[r], w0.x, acc[r][0]);
          acc[r][1] = fmaf(xv[r], w0.y, acc[r][1]);
          acc[r][2] = fmaf(xv[r], w0.z, acc[r][2]);
          acc[r][3] = fmaf(xv[r], w0.w, acc[r][3]);
          acc[r][4] = fmaf(xv[r], w1.x, acc[r][4]);
          acc[r][5] = fmaf(xv[r], w1.y, acc[r][5]);
          acc[r][6] = fmaf(xv[r], w1.z, acc[r][6]);
          acc[r][7] = fmaf(xv[r], w1.w, acc[r][7]);
        }
      } else {
        float xv = xs[k][rg];
        acc[0][0] = fmaf(xv, w0.x, acc[0][0]);
        acc[0][1] = fmaf(xv, w0.y, acc[0][1]);
        acc[0][2] = fmaf(xv, w0.z, acc[0][2]);
        acc[0][3] = fmaf(xv, w0.w, acc[0][3]);
        acc[0][4] = fmaf(xv, w1.x, acc[0][4]);
        acc[0][5] = fmaf(xv, w1.y, acc[0][5]);
        acc[0][6] = fmaf(xv, w1.z, acc[0][6]);
        acc[0][7] = fmaf(xv, w1.w, acc[0][7]);
      }
    }
    __syncthreads();
  }
#pragma unroll
  for (int r = 0; r < RPT; ++r) {
    int row = row0 + rg * RPT + r;
    if (row < NN) {
      __half2* o = (__half2*)Hout + ((size_t)row * CN + c0) / 2;
#pragma unroll
      for (int i = 0; i < 4; ++i)
        o[i] = __floats2half2_rn(acc[r][2 * i], acc[r][2 * i + 1]);
    }
  }
}

// ============ per-node attention coefficients (fp16 h, half2 loads) ============
template <int F>   // 128 or 32
__global__ void attn_coef(const __half* __restrict__ Hf, const float* __restrict__ a_s,
                          const float* __restrict__ a_d, float* __restrict__ al_s,
                          float* __restrict__ al_d) {
  constexpr int TPN = F / 2;     // threads per node: 64 or 16
  const int t = threadIdx.x % TPN;
  const int node = (blockIdx.x * 256 + threadIdx.x) / TPN;
  if (node >= NN) return;
  __half2 hv = ((const __half2*)Hf)[(size_t)node * TPN + t];
  float hx = __low2float(hv), hy = __high2float(hv);
  float ps = hx * a_s[2 * t] + hy * a_s[2 * t + 1];
  float pd = hx * a_d[2 * t] + hy * a_d[2 * t + 1];
#pragma unroll
  for (int off = 8; off >= 1; off >>= 1) {   // reduce the 16-thread head group
    ps += __shfl_xor(ps, off, 64);
    pd += __shfl_xor(pd, off, 64);
  }
  if ((t & 15) == 0) {
    al_s[node * (F / 32) + (t >> 4)] = ps;
    al_d[node * (F / 32) + (t >> 4)] = pd;
  }
}

// ============ fused softmax + aggregation, H=4: one wave/node, fp16 row gathers ============
// lane covers channel pair (2*lane, 2*lane+1); its head = lane>>4, which matches the
// stats mapping (el=lane&15, hh=lane>>4) -> per-head denom is a 16-lane xor reduce.
// No max-subtraction: logits are O(+-10) at this data scale; exp() safe in f32.
__global__ void gat_agg_h4(const int* __restrict__ rp, const int* __restrict__ ssrc,
                           const __half2* __restrict__ Hf2, const float* __restrict__ alS,
                           const float* __restrict__ alD, const float* __restrict__ bias,
                           float* __restrict__ outf) {
  int node = (blockIdx.x * 256 + threadIdx.x) >> 6;
  int lane = threadIdx.x & 63;
  if (node >= NN) return;
  int beg = rp[node], end = rp[node + 1];
  int el = lane & 15, hh = lane >> 4;
  float ad_h = alD[node * 4 + hh];
  float accx = 0.f, accy = 0.f, sm = 0.f;
  for (int ch = beg; ch < end; ch += 16) {
    int cnt = end - ch;
    int sv = node; float ev = 0.f;
    if (el < cnt) {
      sv = ssrc[ch + el];
      float x = alS[sv * 4 + hh] + ad_h;
      x = x > 0.f ? x : SLOPE * x;
      ev = __expf(x);
      sm += ev;
    }
    int sarr[16]; float av[16];
#pragma unroll
    for (int e = 0; e < 16; ++e) {
      sarr[e] = __shfl(sv, e, 64);             // lane e holds (el=e, hh=0)
      av[e]   = __shfl(ev, hh * 16 + e, 64);   // alpha numerator for my head
    }
    __half2 hv[16];
#pragma unroll
    for (int e = 0; e < 16; ++e)               // 16 coalesced row gathers in flight
      hv[e] = Hf2[(size_t)sarr[e] * 64 + lane];
#pragma unroll
    for (int e = 0; e < 16; ++e) {
      accx = fmaf(__low2float(hv[e]),  av[e], accx);
      accy = fmaf(__high2float(hv[e]), av[e], accy);
    }
  }
#pragma unroll
  for (int off = 8; off >= 1; off >>= 1) sm += __shfl_xor(sm, off, 64);  // head denom
  float inv = 1.0f / sm;
  float vx = accx * inv + bias[2 * lane];
  float vy = accy * inv + bias[2 * lane + 1];
  vx = vx > 0.f ? vx : expm1f(vx);
  vy = vy > 0.f ? vy : expm1f(vy);
  ((float2*)outf)[(size_t)node * 64 + lane] = float2{vx, vy};
}

// ============ fused softmax + aggregation, H=1 (F=32): 16 lanes/node ============
__global__ void gat_agg_h1(const int* __restrict__ rp, const int* __restrict__ ssrc,
                           const __half2* __restrict__ Hf2, const float* __restrict__ alS,
                           const float* __restrict__ alD, const float* __restrict__ bias,
                           float* __restrict__ outf) {
  int node = (blockIdx.x * 256 + threadIdx.x) >> 4;
  int lane = threadIdx.x & 15;
  if (node >= NN) return;
  int beg = rp[node], end = rp[node + 1];
  float ad = alD[node];
  float accx = 0.f, accy = 0.f, sm = 0.f;
  for (int ch = beg; ch < end; ch += 16) {
    int cnt = end - ch;
    int sv = node; float ev = 0.f;
    if (lane < cnt) {
      sv = ssrc[ch + lane];
      float x = alS[sv] + ad;
      x = x > 0.f ? x : SLOPE * x;
      ev = __expf(x);
      sm += ev;
    }
    int sarr[16]; float av[16];
#pragma unroll
    for (int e = 0; e < 16; ++e) {
      sarr[e] = __shfl(sv, e, 16);
      av[e]   = __shfl(ev, e, 16);
    }
    __half2 hv[16];
#pragma unroll
    for (int e = 0; e < 16; ++e) hv[e] = Hf2[(size_t)sarr[e] * 16 + lane];
#pragma unroll
    for (int e = 0; e < 16; ++e) {
      accx = fmaf(__low2float(hv[e]),  av[e], accx);
      accy = fmaf(__high2float(hv[e]), av[e], accy);
    }
  }
#pragma unroll
  for (int off = 8; off >= 1; off >>= 1) sm += __shfl_xor(sm, off, 16);
  float inv = 1.0f / sm;
  float vx = accx * inv + bias[2 * lane];
  float vy = accy * inv + bias[2 * lane + 1];
  vx = vx > 0.f ? vx : expm1f(vx);
  vy = vy > 0.f ? vy : expm1f(vy);
  ((float2*)outf)[(size_t)node * 16 + lane] = float2{vx, vy};
}

// ======================= pool (sorted batch -> no atomics) + heads =======================
__device__ __forceinline__ int lb_batch(const int* __restrict__ b, int val) {
  int lo = 0, hi = NN;
  while (lo < hi) { int mid = (lo + hi) >> 1; if (b[mid] < val) lo = mid + 1; else hi = mid; }
  return lo;
}

__global__ void pool_kernel(const float* __restrict__ feat, const int* __restrict__ batch,
                            float* __restrict__ pooled) {
  int g = blockIdx.x;
  int start = lb_batch(batch, g), end = lb_batch(batch, g + 1);
  int c = threadIdx.x & 31, sub = threadIdx.x >> 5;
  float acc = 0.f;
  for (int n = start + sub; n < end; n += 8) acc += feat[(size_t)n * 32 + c];
  __shared__ float red[8][32];
  red[sub][c] = acc;
  __syncthreads();
  if (threadIdx.x < 32) {
    float s = 0.f;
#pragma unroll
    for (int i = 0; i < 8; ++i) s += red[i][c];
    pooled[g * 32 + c] = s / fmaxf((float)(end - start), 1.0f);
  }
}

__global__ void head_kernel(const float* __restrict__ pooled,
                            const float* __restrict__ Wmu, const float* __restrict__ bmu,
                            const float* __restrict__ Wlv, const float* __restrict__ blv,
                            float* __restrict__ out) {
  int idx = blockIdx.x * 256 + threadIdx.x;
  if (idx >= NG * NLAT) return;
  int g = idx / NLAT, l = idx % NLAT;
  float mu = bmu[l], lv = blv[l];
#pragma unroll
  for (int k = 0; k < 32; ++k) {
    float p = pooled[g * 32 + k];
    mu = fmaf(p, Wmu[k * NLAT + l], mu);
    lv = fmaf(p, Wlv[k * NLAT + l], lv);
  }
  out[g * NLAT + l] = mu;
  out[NG * NLAT + g * NLAT + l] = lv;
}

extern "C" void kernel_launch(void* const* d_in, const int* in_sizes, int n_in,
                              void* d_out, int out_size, void* d_ws, size_t ws_size,
                              hipStream_t stream) {
  const float* x     = (const float*)d_in[0];
  const float* W1    = (const float*)d_in[1];
  const float* as1   = (const float*)d_in[2];
  const float* ad1   = (const float*)d_in[3];
  const float* b1    = (const float*)d_in[4];
  const float* W2    = (const float*)d_in[5];
  const float* as2   = (const float*)d_in[6];
  const float* ad2   = (const float*)d_in[7];
  const float* b2    = (const float*)d_in[8];
  const float* W3    = (const float*)d_in[9];
  const float* as3   = (const float*)d_in[10];
  const float* ad3   = (const float*)d_in[11];
  const float* b3    = (const float*)d_in[12];
  const float* Wmu   = (const float*)d_in[13];
  const float* bmu   = (const float*)d_in[14];
  const float* Wlv   = (const float*)d_in[15];
  const float* blv   = (const float*)d_in[16];
  const int*   ei    = (const int*)d_in[17];
  const int*   batch = (const int*)d_in[18];
  float* out = (float*)d_out;

  float* ws    = (float*)d_ws;
  __half* A    = (__half*)ws;                 // [N,128] fp16 h buffer (= NN*64 float slots)
  float* B     = ws + (size_t)NN * 64;        // [N,128] f32 agg/feature buffer
  float* alS   = B + (size_t)NN * 128;        // [N,4]
  float* alD   = alS + (size_t)NN * 4;        // [N,4]
  float* pooled= alD + (size_t)NN * 4;        // [G,32]
  int* deg     = (int*)(pooled + (size_t)NG * 32);  // [N]
  int* rp      = deg + NN;                    // [N+1]
  int* cursor  = rp + NN + 1;                 // [N]
  int* incl    = cursor + NN;                 // [N]
  int* bsum    = incl + NN;                   // [256]
  int* ssrc    = bsum + 256;                  // [NET]

  dim3 blk(256);
  const int EG  = (NET + 255) / 256;
  const int SCB = (NN + 255) / 256;
  const int GB  = (NN + 63) / 64;

  // ---------------- CSR build ----------------
  hipMemsetAsync(deg, 0, (size_t)NN * sizeof(int), stream);
  hist_kernel<<<EG, blk, 0, stream>>>(ei, deg);
  scan_a<<<SCB, blk, 0, stream>>>(deg, incl, bsum);
  scan_b<<<1, blk, 0, stream>>>(bsum, SCB);
  scan_c<<<SCB, blk, 0, stream>>>(incl, bsum, deg, rp, cursor);
  scatter_kernel<<<EG, blk, 0, stream>>>(ei, cursor, ssrc);

  // ---------------- layer 1 ----------------
  gemm_tile<128><<<GB, blk, 0, stream>>>(x, W1, A);
  attn_coef<128><<<(NN * 64) / 256, blk, 0, stream>>>(A, as1, ad1, alS, alD);
  gat_agg_h4<<<(NN * 64) / 256, blk, 0, stream>>>(rp, ssrc, (const __half2*)A, alS, alD, b1, B);
  // ---------------- layer 2 ----------------
  gemm_tile<128><<<GB, blk, 0, stream>>>(B, W2, A);
  attn_coef<128><<<(NN * 64) / 256, blk, 0, stream>>>(A, as2, ad2, alS, alD);
  gat_agg_h4<<<(NN * 64) / 256, blk, 0, stream>>>(rp, ssrc, (const __half2*)A, alS, alD, b2, B);
  // ---------------- layer 3 ----------------
  gemm_tile<32><<<GB, blk, 0, stream>>>(B, W3, A);   // A as [N,32] fp16
  attn_coef<32><<<(NN * 16) / 256, blk, 0, stream>>>(A, as3, ad3, alS, alD);
  gat_agg_h1<<<(NN * 16) / 256, blk, 0, stream>>>(rp, ssrc, (const __half2*)A, alS, alD, b3, B);

  // ---------------- pool + heads ----------------
  pool_kernel<<<NG, blk, 0, stream>>>(B, batch, pooled);
  head_kernel<<<(NG * NLAT + 255) / 256, blk, 0, stream>>>(pooled, Wmu, bmu, Wlv, blv, out);
}

// Round 6
// 245.438 us; speedup vs baseline: 2.6765x; 1.2392x over previous
//
#include <hip/hip_runtime.h>
#include <hip/hip_fp16.h>

constexpr int NN   = 50000;            // nodes
constexpr int NE   = 800000;           // edges (before self-loops; self-loops handled analytically)
constexpr int NG   = 512;              // graphs
constexpr int NLAT = 64;               // latent dim
constexpr float SLOPE = 0.2f;          // leaky relu slope

constexpr int NBK  = 196;              // coarse buckets of 256 nodes (ceil(NN/256))
constexpr int BCAP = 8192;             // per-bucket capacity (avg 4082, Poisson; 8192 is >>5 sigma)
constexpr int EPB  = 4096;             // edges per pass-1 block
constexpr int NB1  = (NE + EPB - 1) / EPB;   // 196

// ============ pass 1: bucket edges by dst>>8 with LDS staging, coalesced write-out ============
__global__ void p1_bucket(const int* __restrict__ ei, int* __restrict__ gcur,
                          unsigned* __restrict__ gbuf) {
  __shared__ unsigned lin[EPB];
  __shared__ unsigned lout[EPB];
  __shared__ int lhist[NBK], lbase[NBK + 1], lcur[NBK], goff[NBK];
  __shared__ int tmp[256];
  const int tid = threadIdx.x;
  if (tid < NBK) lhist[tid] = 0;
  __syncthreads();
  const int e0 = blockIdx.x * EPB;
#pragma unroll
  for (int i = 0; i < EPB / 256; ++i) {
    int e = e0 + i * 256 + tid;
    unsigned p = 0xFFFFFFFFu;
    if (e < NE) {
      int s = ei[e], d = ei[NE + e];
      p = ((unsigned)(d >> 8) << 24) | ((unsigned)(d & 255) << 16) | (unsigned)s;  // src<65536
      atomicAdd(&lhist[d >> 8], 1);
    }
    lin[i * 256 + tid] = p;
  }
  __syncthreads();
  int v = (tid < NBK) ? lhist[tid] : 0;
  tmp[tid] = v;
  __syncthreads();
  for (int off = 1; off < 256; off <<= 1) {
    int t = (tid >= off) ? tmp[tid - off] : 0;
    __syncthreads();
    tmp[tid] += t;
    __syncthreads();
  }
  if (tid < NBK) { lbase[tid] = tmp[tid] - v; lcur[tid] = tmp[tid] - v; }
  if (tid == NBK - 1) lbase[NBK] = tmp[NBK - 1];
  __syncthreads();
#pragma unroll
  for (int i = 0; i < EPB / 256; ++i) {
    unsigned p = lin[i * 256 + tid];
    if (p != 0xFFFFFFFFu) {
      int b = p >> 24;
      int pos = atomicAdd(&lcur[b], 1);
      lout[pos] = p & 0xFFFFFFu;               // keep (d_local<<16 | src)
    }
  }
  if (tid < NBK) goff[tid] = atomicAdd(&gcur[tid], lhist[tid]);
  __syncthreads();
  const int total = lbase[NBK];
  for (int i = tid; i < total; i += 256) {
    int lo = 0, hi = NBK - 1;                  // largest b with lbase[b] <= i
    while (lo < hi) { int mid = (lo + hi + 1) >> 1; if (lbase[mid] <= i) lo = mid; else hi = mid - 1; }
    gbuf[(size_t)lo * BCAP + goff[lo] + (i - lbase[lo])] = lout[i];
  }
}

// ============ tiny scan over bucket counts -> bucket bases; also rp[NN] ============
__global__ void scan_buckets(const int* __restrict__ gcur, int* __restrict__ bbase,
                             int* __restrict__ rp) {
  __shared__ int tmp[256];
  const int tid = threadIdx.x;
  int v = (tid < NBK) ? gcur[tid] : 0;
  tmp[tid] = v;
  __syncthreads();
  for (int off = 1; off < 256; off <<= 1) {
    int t = (tid >= off) ? tmp[tid - off] : 0;
    __syncthreads();
    tmp[tid] += t;
    __syncthreads();
  }
  if (tid < NBK) bbase[tid] = tmp[tid] - v;
  if (tid == 0) rp[NN] = NE;
}

// ============ pass 2: per-bucket counting sort in LDS -> rp + coalesced ssrc ============
__global__ void p2_sort(const unsigned* __restrict__ gbuf, const int* __restrict__ gcur,
                        const int* __restrict__ bbase, int* __restrict__ rp,
                        int* __restrict__ ssrc) {
  __shared__ unsigned lin[BCAP];
  __shared__ unsigned short lsorted[BCAP];
  __shared__ int lhist[256], lcur2[256];
  __shared__ int tmp[256];
  const int tid = threadIdx.x;
  const int b = blockIdx.x;
  const int cnt = min(gcur[b], BCAP);
  const int base = bbase[b];
  lhist[tid] = 0;
  __syncthreads();
  for (int i = tid; i < cnt; i += 256) {
    unsigned p = gbuf[(size_t)b * BCAP + i];
    lin[i] = p;
    atomicAdd(&lhist[(p >> 16) & 255], 1);
  }
  __syncthreads();
  int v = lhist[tid];
  tmp[tid] = v;
  __syncthreads();
  for (int off = 1; off < 256; off <<= 1) {
    int t = (tid >= off) ? tmp[tid - off] : 0;
    __syncthreads();
    tmp[tid] += t;
    __syncthreads();
  }
  lcur2[tid] = tmp[tid] - v;
  int node = b * 256 + tid;
  if (node < NN) rp[node] = base + tmp[tid] - v;
  __syncthreads();
  for (int i = tid; i < cnt; i += 256) {
    unsigned p = lin[i];
    int pos = atomicAdd(&lcur2[(p >> 16) & 255], 1);
    lsorted[pos] = (unsigned short)(p & 0xFFFFu);
  }
  __syncthreads();
  for (int i = tid; i < cnt; i += 256) ssrc[base + i] = (int)lsorted[i];
}

// ============ tiled GEMM: C[n,j] = sum_k X[n,k] W[k,j]; K=128, BM=64; fp16 output ============
template <int CN>   // 128 or 32
__global__ void gemm_tile(const float* __restrict__ X, const float* __restrict__ W,
                          __half* __restrict__ Hout) {
  constexpr int CG  = CN / 8;       // col-groups: 16 or 4
  constexpr int RG  = 256 / CG;     // row-groups: 16 or 64
  constexpr int RPT = 64 / RG;      // rows/thread: 4 or 1
  __shared__ float xs[32][68];      // [k][row]
  __shared__ float ws[32][CN + 4];  // [k][col]
  const int rg = threadIdx.x % RG;
  const int cg = threadIdx.x / RG;
  const int row0 = blockIdx.x * 64;
  const int c0 = cg * 8;
  float acc[RPT][8];
#pragma unroll
  for (int r = 0; r < RPT; ++r)
#pragma unroll
    for (int c = 0; c < 8; ++c) acc[r][c] = 0.f;

  for (int chunk = 0; chunk < 4; ++chunk) {
#pragma unroll
    for (int j = 0; j < 2; ++j) {
      int idx = threadIdx.x + j * 256;
      int r = idx >> 3, s = idx & 7;
      int gr = row0 + r;
      float4 v = (gr < NN) ? *(const float4*)(X + (size_t)gr * 128 + chunk * 32 + s * 4)
                           : float4{0.f, 0.f, 0.f, 0.f};
      xs[s * 4 + 0][r] = v.x;
      xs[s * 4 + 1][r] = v.y;
      xs[s * 4 + 2][r] = v.z;
      xs[s * 4 + 3][r] = v.w;
    }
#pragma unroll
    for (int j = 0; j < 32 * CN / 1024; ++j) {
      int idx = threadIdx.x + j * 256;
      int k = idx / (CN / 4), s = idx % (CN / 4);
      *(float4*)&ws[k][s * 4] =
          *(const float4*)(W + (size_t)(chunk * 32 + k) * CN + s * 4);
    }
    __syncthreads();
#pragma unroll 4
    for (int k = 0; k < 32; ++k) {
      float4 w0 = *(const float4*)&ws[k][c0];
      float4 w1 = *(const float4*)&ws[k][c0 + 4];
      if constexpr (RPT == 4) {
        float4 xa = *(const float4*)&xs[k][rg * 4];
        float xv[4] = {xa.x, xa.y, xa.z, xa.w};
#pragma unroll
        for (int r = 0; r < 4; ++r) {
          acc[r][0] = fmaf(xv[r], w0.x, acc[r][0]);
          acc[r][1] = fmaf(xv[r], w0.y, acc[r][1]);
          acc[r][2] = fmaf(xv[r], w0.z, acc[r][2]);
          acc[r][3] = fmaf(xv[r], w0.w, acc[r][3]);
          acc[r][4] = fmaf(xv[r], w1.x, acc[r][4]);
          acc[r][5] = fmaf(xv[r], w1.y, acc[r][5]);
          acc[r][6] = fmaf(xv[r], w1.z, acc[r][6]);
          acc[r][7] = fmaf(xv[r], w1.w, acc[r][7]);
        }
      } else {
        float xv = xs[k][rg];
        acc[0][0] = fmaf(xv, w0.x, acc[0][0]);
        acc[0][1] = fmaf(xv, w0.y, acc[0][1]);
        acc[0][2] = fmaf(xv, w0.z, acc[0][2]);
        acc[0][3] = fmaf(xv, w0.w, acc[0][3]);
        acc[0][4] = fmaf(xv, w1.x, acc[0][4]);
        acc[0][5] = fmaf(xv, w1.y, acc[0][5]);
        acc[0][6] = fmaf(xv, w1.z, acc[0][6]);
        acc[0][7] = fmaf(xv, w1.w, acc[0][7]);
      }
    }
    __syncthreads();
  }
#pragma unroll
  for (int r = 0; r < RPT; ++r) {
    int row = row0 + rg * RPT + r;
    if (row < NN) {
      __half2* o = (__half2*)Hout + ((size_t)row * CN + c0) / 2;
#pragma unroll
      for (int i = 0; i < 4; ++i)
        o[i] = __floats2half2_rn(acc[r][2 * i], acc[r][2 * i + 1]);
    }
  }
}

// ============ per-node attention coefficients (fp16 h, half2 loads) ============
template <int F>   // 128 or 32
__global__ void attn_coef(const __half* __restrict__ Hf, const float* __restrict__ a_s,
                          const float* __restrict__ a_d, float* __restrict__ al_s,
                          float* __restrict__ al_d) {
  constexpr int TPN = F / 2;     // threads per node: 64 or 16
  const int t = threadIdx.x % TPN;
  const int node = (blockIdx.x * 256 + threadIdx.x) / TPN;
  if (node >= NN) return;
  __half2 hv = ((const __half2*)Hf)[(size_t)node * TPN + t];
  float hx = __low2float(hv), hy = __high2float(hv);
  float ps = hx * a_s[2 * t] + hy * a_s[2 * t + 1];
  float pd = hx * a_d[2 * t] + hy * a_d[2 * t + 1];
#pragma unroll
  for (int off = 8; off >= 1; off >>= 1) {   // reduce the 16-thread head group
    ps += __shfl_xor(ps, off, 64);
    pd += __shfl_xor(pd, off, 64);
  }
  if ((t & 15) == 0) {
    al_s[node * (F / 32) + (t >> 4)] = ps;
    al_d[node * (F / 32) + (t >> 4)] = pd;
  }
}

// ============ fused softmax + aggregation, H=4: one wave/node; self-loop analytic ============
// lane covers channel pair (2*lane, 2*lane+1); head = lane>>4 = stats-lane head.
// No max-subtraction: logits are O(+-10) at this data scale; exp() safe in f32.
__global__ void gat_agg_h4(const int* __restrict__ rp, const int* __restrict__ ssrc,
                           const __half2* __restrict__ Hf2, const float* __restrict__ alS,
                           const float* __restrict__ alD, const float* __restrict__ bias,
                           float* __restrict__ outf) {
  int node = (blockIdx.x * 256 + threadIdx.x) >> 6;
  int lane = threadIdx.x & 63;
  if (node >= NN) return;
  int beg = rp[node], end = rp[node + 1];
  int el = lane & 15, hh = lane >> 4;
  float ad_h = alD[node * 4 + hh];
  // self-loop contribution (once per head in sm; per-lane channels in acc)
  float xsf = alS[node * 4 + hh] + ad_h;
  xsf = xsf > 0.f ? xsf : SLOPE * xsf;
  float evs = __expf(xsf);
  __half2 hself = Hf2[(size_t)node * 64 + lane];
  float accx = __low2float(hself) * evs;
  float accy = __high2float(hself) * evs;
  float sm = (el == 0) ? evs : 0.f;
  for (int ch = beg; ch < end; ch += 16) {
    int cnt = end - ch;
    int sv = node; float ev = 0.f;
    if (el < cnt) {
      sv = ssrc[ch + el];
      float x = alS[sv * 4 + hh] + ad_h;
      x = x > 0.f ? x : SLOPE * x;
      ev = __expf(x);
      sm += ev;
    }
    int sarr[16]; float av[16];
#pragma unroll
    for (int e = 0; e < 16; ++e) {
      sarr[e] = __shfl(sv, e, 64);             // lane e holds (el=e, hh=0)
      av[e]   = __shfl(ev, hh * 16 + e, 64);   // alpha numerator for my head
    }
    __half2 hv[16];
#pragma unroll
    for (int e = 0; e < 16; ++e)               // 16 coalesced row gathers in flight
      hv[e] = Hf2[(size_t)sarr[e] * 64 + lane];
#pragma unroll
    for (int e = 0; e < 16; ++e) {
      accx = fmaf(__low2float(hv[e]),  av[e], accx);
      accy = fmaf(__high2float(hv[e]), av[e], accy);
    }
  }
#pragma unroll
  for (int off = 8; off >= 1; off >>= 1) sm += __shfl_xor(sm, off, 64);  // head denom
  float inv = 1.0f / sm;
  float vx = accx * inv + bias[2 * lane];
  float vy = accy * inv + bias[2 * lane + 1];
  vx = vx > 0.f ? vx : expm1f(vx);
  vy = vy > 0.f ? vy : expm1f(vy);
  ((float2*)outf)[(size_t)node * 64 + lane] = float2{vx, vy};
}

// ============ fused softmax + aggregation, H=1 (F=32): 16 lanes/node; self-loop analytic ============
__global__ void gat_agg_h1(const int* __restrict__ rp, const int* __restrict__ ssrc,
                           const __half2* __restrict__ Hf2, const float* __restrict__ alS,
                           const float* __restrict__ alD, const float* __restrict__ bias,
                           float* __restrict__ outf) {
  int node = (blockIdx.x * 256 + threadIdx.x) >> 4;
  int lane = threadIdx.x & 15;
  if (node >= NN) return;
  int beg = rp[node], end = rp[node + 1];
  float ad = alD[node];
  float xsf = alS[node] + ad;
  xsf = xsf > 0.f ? xsf : SLOPE * xsf;
  float evs = __expf(xsf);
  __half2 hself = Hf2[(size_t)node * 16 + lane];
  float accx = __low2float(hself) * evs;
  float accy = __high2float(hself) * evs;
  float sm = (lane == 0) ? evs : 0.f;
  for (int ch = beg; ch < end; ch += 16) {
    int cnt = end - ch;
    int sv = node; float ev = 0.f;
    if (lane < cnt) {
      sv = ssrc[ch + lane];
      float x = alS[sv] + ad;
      x = x > 0.f ? x : SLOPE * x;
      ev = __expf(x);
      sm += ev;
    }
    int sarr[16]; float av[16];
#pragma unroll
    for (int e = 0; e < 16; ++e) {
      sarr[e] = __shfl(sv, e, 16);
      av[e]   = __shfl(ev, e, 16);
    }
    __half2 hv[16];
#pragma unroll
    for (int e = 0; e < 16; ++e) hv[e] = Hf2[(size_t)sarr[e] * 16 + lane];
#pragma unroll
    for (int e = 0; e < 16; ++e) {
      accx = fmaf(__low2float(hv[e]),  av[e], accx);
      accy = fmaf(__high2float(hv[e]), av[e], accy);
    }
  }
#pragma unroll
  for (int off = 8; off >= 1; off >>= 1) sm += __shfl_xor(sm, off, 16);
  float inv = 1.0f / sm;
  float vx = accx * inv + bias[2 * lane];
  float vy = accy * inv + bias[2 * lane + 1];
  vx = vx > 0.f ? vx : expm1f(vx);
  vy = vy > 0.f ? vy : expm1f(vy);
  ((float2*)outf)[(size_t)node * 16 + lane] = float2{vx, vy};
}

// ======================= pool (sorted batch -> no atomics) + heads =======================
__device__ __forceinline__ int lb_batch(const int* __restrict__ b, int val) {
  int lo = 0, hi = NN;
  while (lo < hi) { int mid = (lo + hi) >> 1; if (b[mid] < val) lo = mid + 1; else hi = mid; }
  return lo;
}

__global__ void pool_kernel(const float* __restrict__ feat, const int* __restrict__ batch,
                            float* __restrict__ pooled) {
  int g = blockIdx.x;
  int start = lb_batch(batch, g), end = lb_batch(batch, g + 1);
  int c = threadIdx.x & 31, sub = threadIdx.x >> 5;
  float acc = 0.f;
  for (int n = start + sub; n < end; n += 8) acc += feat[(size_t)n * 32 + c];
  __shared__ float red[8][32];
  red[sub][c] = acc;
  __syncthreads();
  if (threadIdx.x < 32) {
    float s = 0.f;
#pragma unroll
    for (int i = 0; i < 8; ++i) s += red[i][c];
    pooled[g * 32 + c] = s / fmaxf((float)(end - start), 1.0f);
  }
}

__global__ void head_kernel(const float* __restrict__ pooled,
                            const float* __restrict__ Wmu, const float* __restrict__ bmu,
                            const float* __restrict__ Wlv, const float* __restrict__ blv,
                            float* __restrict__ out) {
  int idx = blockIdx.x * 256 + threadIdx.x;
  if (idx >= NG * NLAT) return;
  int g = idx / NLAT, l = idx % NLAT;
  float mu = bmu[l], lv = blv[l];
#pragma unroll
  for (int k = 0; k < 32; ++k) {
    float p = pooled[g * 32 + k];
    mu = fmaf(p, Wmu[k * NLAT + l], mu);
    lv = fmaf(p, Wlv[k * NLAT + l], lv);
  }
  out[g * NLAT + l] = mu;
  out[NG * NLAT + g * NLAT + l] = lv;
}

extern "C" void kernel_launch(void* const* d_in, const int* in_sizes, int n_in,
                              void* d_out, int out_size, void* d_ws, size_t ws_size,
                              hipStream_t stream) {
  const float* x     = (const float*)d_in[0];
  const float* W1    = (const float*)d_in[1];
  const float* as1   = (const float*)d_in[2];
  const float* ad1   = (const float*)d_in[3];
  const float* b1    = (const float*)d_in[4];
  const float* W2    = (const float*)d_in[5];
  const float* as2   = (const float*)d_in[6];
  const float* ad2   = (const float*)d_in[7];
  const float* b2    = (const float*)d_in[8];
  const float* W3    = (const float*)d_in[9];
  const float* as3   = (const float*)d_in[10];
  const float* ad3   = (const float*)d_in[11];
  const float* b3    = (const float*)d_in[12];
  const float* Wmu   = (const float*)d_in[13];
  const float* bmu   = (const float*)d_in[14];
  const float* Wlv   = (const float*)d_in[15];
  const float* blv   = (const float*)d_in[16];
  const int*   ei    = (const int*)d_in[17];
  const int*   batch = (const int*)d_in[18];
  float* out = (float*)d_out;

  float* ws    = (float*)d_ws;
  __half* A    = (__half*)ws;                 // [N,128] fp16 h buffer (= NN*64 float slots)
  float* B     = ws + (size_t)NN * 64;        // [N,128] f32 agg/feature buffer
  float* alS   = B + (size_t)NN * 128;        // [N,4]
  float* alD   = alS + (size_t)NN * 4;        // [N,4]
  float* pooled= alD + (size_t)NN * 4;        // [G,32]
  int* rp      = (int*)(pooled + (size_t)NG * 32);  // [N+1]
  int* gcur    = rp + NN + 1;                 // [256]
  int* bbase   = gcur + 256;                  // [256]
  unsigned* gbuf = (unsigned*)(bbase + 256);  // [NBK*BCAP]
  int* ssrc    = (int*)(gbuf + (size_t)NBK * BCAP);  // [NE]

  dim3 blk(256);

  // ---------------- CSR build (LDS bucket sort; coalesced writes) ----------------
  hipMemsetAsync(gcur, 0, 256 * sizeof(int), stream);
  p1_bucket<<<NB1, blk, 0, stream>>>(ei, gcur, gbuf);
  scan_buckets<<<1, blk, 0, stream>>>(gcur, bbase, rp);
  p2_sort<<<NBK, blk, 0, stream>>>(gbuf, gcur, bbase, rp, ssrc);

  const int GB = (NN + 63) / 64;
  // ---------------- layer 1 ----------------
  gemm_tile<128><<<GB, blk, 0, stream>>>(x, W1, A);
  attn_coef<128><<<(NN * 64) / 256, blk, 0, stream>>>(A, as1, ad1, alS, alD);
  gat_agg_h4<<<(NN * 64) / 256, blk, 0, stream>>>(rp, ssrc, (const __half2*)A, alS, alD, b1, B);
  // ---------------- layer 2 ----------------
  gemm_tile<128><<<GB, blk, 0, stream>>>(B, W2, A);
  attn_coef<128><<<(NN * 64) / 256, blk, 0, stream>>>(A, as2, ad2, alS, alD);
  gat_agg_h4<<<(NN * 64) / 256, blk, 0, stream>>>(rp, ssrc, (const __half2*)A, alS, alD, b2, B);
  // ---------------- layer 3 ----------------
  gemm_tile<32><<<GB, blk, 0, stream>>>(B, W3, A);   // A as [N,32] fp16
  attn_coef<32><<<(NN * 16) / 256, blk, 0, stream>>>(A, as3, ad3, alS, alD);
  gat_agg_h1<<<(NN * 16) / 256, blk, 0, stream>>>(rp, ssrc, (const __half2*)A, alS, alD, b3, B);

  // ---------------- pool + heads ----------------
  pool_kernel<<<NG, blk, 0, stream>>>(B, batch, pooled);
  head_kernel<<<(NG * NLAT + 255) / 256, blk, 0, stream>>>(pooled, Wmu, bmu, Wlv, blv, out);
}

// Round 7
// 206.276 us; speedup vs baseline: 3.1847x; 1.1899x over previous
//
#include <hip/hip_runtime.h>
#include <hip/hip_fp16.h>

constexpr int NN   = 50000;            // nodes
constexpr int NE   = 800000;           // edges (self-loops handled analytically)
constexpr int NG   = 512;              // graphs
constexpr int NLAT = 64;               // latent dim
constexpr float SLOPE = 0.2f;          // leaky relu slope

constexpr int NBK  = 196;              // coarse buckets of 256 nodes
constexpr int BCAP = 8192;             // per-bucket capacity
constexpr int EPB  = 4096;             // edges per pass-1 block
constexpr int NB1  = (NE + EPB - 1) / EPB;   // 196

typedef _Float16 h8 __attribute__((ext_vector_type(8)));
typedef float f32x4 __attribute__((ext_vector_type(4)));

// ======================= CSR build: LDS bucket sort (round-6, unchanged) =======================
__global__ void p1_bucket(const int* __restrict__ ei, int* __restrict__ gcur,
                          unsigned* __restrict__ gbuf) {
  __shared__ unsigned lin[EPB];
  __shared__ unsigned lout[EPB];
  __shared__ int lhist[NBK], lbase[NBK + 1], lcur[NBK], goff[NBK];
  __shared__ int tmp[256];
  const int tid = threadIdx.x;
  if (tid < NBK) lhist[tid] = 0;
  __syncthreads();
  const int e0 = blockIdx.x * EPB;
#pragma unroll
  for (int i = 0; i < EPB / 256; ++i) {
    int e = e0 + i * 256 + tid;
    unsigned p = 0xFFFFFFFFu;
    if (e < NE) {
      int s = ei[e], d = ei[NE + e];
      p = ((unsigned)(d >> 8) << 24) | ((unsigned)(d & 255) << 16) | (unsigned)s;
      atomicAdd(&lhist[d >> 8], 1);
    }
    lin[i * 256 + tid] = p;
  }
  __syncthreads();
  int v = (tid < NBK) ? lhist[tid] : 0;
  tmp[tid] = v;
  __syncthreads();
  for (int off = 1; off < 256; off <<= 1) {
    int t = (tid >= off) ? tmp[tid - off] : 0;
    __syncthreads();
    tmp[tid] += t;
    __syncthreads();
  }
  if (tid < NBK) { lbase[tid] = tmp[tid] - v; lcur[tid] = tmp[tid] - v; }
  if (tid == NBK - 1) lbase[NBK] = tmp[NBK - 1];
  __syncthreads();
#pragma unroll
  for (int i = 0; i < EPB / 256; ++i) {
    unsigned p = lin[i * 256 + tid];
    if (p != 0xFFFFFFFFu) {
      int b = p >> 24;
      int pos = atomicAdd(&lcur[b], 1);
      lout[pos] = p & 0xFFFFFFu;
    }
  }
  if (tid < NBK) goff[tid] = atomicAdd(&gcur[tid], lhist[tid]);
  __syncthreads();
  const int total = lbase[NBK];
  for (int i = tid; i < total; i += 256) {
    int lo = 0, hi = NBK - 1;
    while (lo < hi) { int mid = (lo + hi + 1) >> 1; if (lbase[mid] <= i) lo = mid; else hi = mid - 1; }
    gbuf[(size_t)lo * BCAP + goff[lo] + (i - lbase[lo])] = lout[i];
  }
}

__global__ void scan_buckets(const int* __restrict__ gcur, int* __restrict__ bbase,
                             int* __restrict__ rp) {
  __shared__ int tmp[256];
  const int tid = threadIdx.x;
  int v = (tid < NBK) ? gcur[tid] : 0;
  tmp[tid] = v;
  __syncthreads();
  for (int off = 1; off < 256; off <<= 1) {
    int t = (tid >= off) ? tmp[tid - off] : 0;
    __syncthreads();
    tmp[tid] += t;
    __syncthreads();
  }
  if (tid < NBK) bbase[tid] = tmp[tid] - v;
  if (tid == 0) rp[NN] = NE;
}

__global__ void p2_sort(const unsigned* __restrict__ gbuf, const int* __restrict__ gcur,
                        const int* __restrict__ bbase, int* __restrict__ rp,
                        int* __restrict__ ssrc) {
  __shared__ unsigned lin[BCAP];
  __shared__ unsigned short lsorted[BCAP];
  __shared__ int lhist[256], lcur2[256];
  __shared__ int tmp[256];
  const int tid = threadIdx.x;
  const int b = blockIdx.x;
  const int cnt = min(gcur[b], BCAP);
  const int base = bbase[b];
  lhist[tid] = 0;
  __syncthreads();
  for (int i = tid; i < cnt; i += 256) {
    unsigned p = gbuf[(size_t)b * BCAP + i];
    lin[i] = p;
    atomicAdd(&lhist[(p >> 16) & 255], 1);
  }
  __syncthreads();
  int v = lhist[tid];
  tmp[tid] = v;
  __syncthreads();
  for (int off = 1; off < 256; off <<= 1) {
    int t = (tid >= off) ? tmp[tid - off] : 0;
    __syncthreads();
    tmp[tid] += t;
    __syncthreads();
  }
  lcur2[tid] = tmp[tid] - v;
  int node = b * 256 + tid;
  if (node < NN) rp[node] = base + tmp[tid] - v;
  __syncthreads();
  for (int i = tid; i < cnt; i += 256) {
    unsigned p = lin[i];
    int pos = atomicAdd(&lcur2[(p >> 16) & 255], 1);
    lsorted[pos] = (unsigned short)(p & 0xFFFFu);
  }
  __syncthreads();
  for (int i = tid; i < cnt; i += 256) ssrc[base + i] = (int)lsorted[i];
}

// ======================= fp16 conversions =======================
__global__ void xcast(const float* __restrict__ x, _Float16* __restrict__ xh) {
  int i = blockIdx.x * 256 + threadIdx.x;            // one per 8 elems
  const int total = NN * 128 / 8;
  if (i >= total) return;
  float4 a = ((const float4*)x)[2 * i];
  float4 b = ((const float4*)x)[2 * i + 1];
  h8 v = {(_Float16)a.x, (_Float16)a.y, (_Float16)a.z, (_Float16)a.w,
          (_Float16)b.x, (_Float16)b.y, (_Float16)b.z, (_Float16)b.w};
  *(h8*)(xh + 8 * i) = v;
}

// W[k][c] f32 -> WT[c][k] fp16 (tiny; one block per output column)
__global__ void wcast(const float* __restrict__ W1, const float* __restrict__ W2,
                      const float* __restrict__ W3, _Float16* __restrict__ WT1,
                      _Float16* __restrict__ WT2, _Float16* __restrict__ WT3) {
  int b = blockIdx.x, k = threadIdx.x;   // 128 threads = K
  if (b < 128)      WT1[b * 128 + k] = (_Float16)W1[k * 128 + b];
  else if (b < 256) { int c = b - 128; WT2[c * 128 + k] = (_Float16)W2[k * 128 + c]; }
  else              { int c = b - 256; WT3[c * 128 + k] = (_Float16)W3[k * 32 + c]; }
}

// ============ MFMA GEMM (K=128): h = X*W, fp16 in/out, f32 accum; fused attn coefs ============
// LDS layout [kc][row][8] matches the 16x16x32 fragment: lane reads 8 contiguous k at
// (row=lane&15, kc=ks*4+lane>>4) via ds_read_b128, 2-way bank conflict (free).
// C/D layout (verified, guide m89): col=lane&15, row=(lane>>4)*4+reg.
template <int CN>   // 128 (H=4) or 32 (H=1)
__global__ void __launch_bounds__(256)
gemm_mfma(const _Float16* __restrict__ X, const _Float16* __restrict__ WT,
          const float* __restrict__ aS, const float* __restrict__ aD,
          _Float16* __restrict__ Hout, float* __restrict__ alS, float* __restrict__ alD) {
  __shared__ _Float16 xt[16 * 64 * 8];     // 16 KB
  __shared__ _Float16 wt[16 * CN * 8];     // 32 KB (CN=128) / 8 KB
  const int tid = threadIdx.x;
  const int row0 = blockIdx.x * 64;
  {  // stage X tile (coalesced 16B loads)
    int r = tid >> 2, q = tid & 3;
    int gr = row0 + r;
    const _Float16* src = X + (size_t)gr * 128 + q * 32;
#pragma unroll
    for (int s = 0; s < 4; ++s) {
      h8 v = {};
      if (gr < NN) v = *(const h8*)(src + s * 8);
      *(h8*)&xt[((q * 4 + s) * 64 + r) * 8] = v;
    }
  }
  if constexpr (CN == 128) {
    int col = tid >> 1, q = tid & 1;
#pragma unroll
    for (int s = 0; s < 8; ++s) {
      int kc = q * 8 + s;
      *(h8*)&wt[(kc * CN + col) * 8] = *(const h8*)(WT + col * 128 + q * 64 + s * 8);
    }
  } else {
    int col = tid >> 3, q = tid & 7;
#pragma unroll
    for (int s = 0; s < 2; ++s) {
      int kc = q * 2 + s;
      *(h8*)&wt[(kc * CN + col) * 8] = *(const h8*)(WT + col * 128 + q * 16 + s * 8);
    }
  }
  __syncthreads();
  const int w = tid >> 6, ln = tid & 15, lg = (tid & 63) >> 4;
  if constexpr (CN == 128) {
    f32x4 acc[4][2] = {};
#pragma unroll
    for (int ks = 0; ks < 4; ++ks) {
      int kc = ks * 4 + lg;
      h8 a[4], b[2];
#pragma unroll
      for (int mt = 0; mt < 4; ++mt) a[mt] = *(const h8*)&xt[(kc * 64 + mt * 16 + ln) * 8];
#pragma unroll
      for (int nt = 0; nt < 2; ++nt) b[nt] = *(const h8*)&wt[(kc * CN + w * 32 + nt * 16 + ln) * 8];
#pragma unroll
      for (int mt = 0; mt < 4; ++mt)
#pragma unroll
        for (int nt = 0; nt < 2; ++nt)
          acc[mt][nt] = __builtin_amdgcn_mfma_f32_16x16x32_f16(a[mt], b[nt], acc[mt][nt], 0, 0, 0);
    }
    // epilogue: wave w == head w; al = dot(h_row, a) reduced over the 16 col-lanes
    int c0 = w * 32 + ln, c1 = c0 + 16;
    float as0 = aS[c0], as1 = aS[c1], ad0 = aD[c0], ad1 = aD[c1];
#pragma unroll
    for (int mt = 0; mt < 4; ++mt) {
#pragma unroll
      for (int i = 0; i < 4; ++i) {
        int row = row0 + mt * 16 + lg * 4 + i;
        float d0 = acc[mt][0][i], d1 = acc[mt][1][i];
        float ps = d0 * as0 + d1 * as1;
        float pd = d0 * ad0 + d1 * ad1;
        ps += __shfl_xor(ps, 1, 64); pd += __shfl_xor(pd, 1, 64);
        ps += __shfl_xor(ps, 2, 64); pd += __shfl_xor(pd, 2, 64);
        ps += __shfl_xor(ps, 4, 64); pd += __shfl_xor(pd, 4, 64);
        ps += __shfl_xor(ps, 8, 64); pd += __shfl_xor(pd, 8, 64);
        if (row < NN) {
          Hout[(size_t)row * 128 + c0] = (_Float16)d0;
          Hout[(size_t)row * 128 + c1] = (_Float16)d1;
          if (ln == 0) { alS[row * 4 + w] = ps; alD[row * 4 + w] = pd; }
        }
      }
    }
  } else {
    f32x4 acc[2] = {};
#pragma unroll
    for (int ks = 0; ks < 4; ++ks) {
      int kc = ks * 4 + lg;
      h8 a = *(const h8*)&xt[(kc * 64 + w * 16 + ln) * 8];
#pragma unroll
      for (int nt = 0; nt < 2; ++nt) {
        h8 b = *(const h8*)&wt[(kc * CN + nt * 16 + ln) * 8];
        acc[nt] = __builtin_amdgcn_mfma_f32_16x16x32_f16(a, b, acc[nt], 0, 0, 0);
      }
    }
    int c0 = ln, c1 = ln + 16;
    float as0 = aS[c0], as1 = aS[c1], ad0 = aD[c0], ad1 = aD[c1];
#pragma unroll
    for (int i = 0; i < 4; ++i) {
      int row = row0 + w * 16 + lg * 4 + i;
      float d0 = acc[0][i], d1 = acc[1][i];
      float ps = d0 * as0 + d1 * as1;
      float pd = d0 * ad0 + d1 * ad1;
      ps += __shfl_xor(ps, 1, 64); pd += __shfl_xor(pd, 1, 64);
      ps += __shfl_xor(ps, 2, 64); pd += __shfl_xor(pd, 2, 64);
      ps += __shfl_xor(ps, 4, 64); pd += __shfl_xor(pd, 4, 64);
      ps += __shfl_xor(ps, 8, 64); pd += __shfl_xor(pd, 8, 64);
      if (row < NN) {
        Hout[(size_t)row * 32 + c0] = (_Float16)d0;
        Hout[(size_t)row * 32 + c1] = (_Float16)d1;
        if (ln == 0) { alS[row] = ps; alD[row] = pd; }
      }
    }
  }
}

// ============ fused softmax + aggregation, H=4: one wave/node; self-loop analytic ============
__global__ void gat_agg_h4(const int* __restrict__ rp, const int* __restrict__ ssrc,
                           const __half2* __restrict__ Hf2, const float* __restrict__ alS,
                           const float* __restrict__ alD, const float* __restrict__ bias,
                           __half2* __restrict__ outf) {
  int node = (blockIdx.x * 256 + threadIdx.x) >> 6;
  int lane = threadIdx.x & 63;
  if (node >= NN) return;
  int beg = rp[node], end = rp[node + 1];
  int el = lane & 15, hh = lane >> 4;
  float ad_h = alD[node * 4 + hh];
  float xsf = alS[node * 4 + hh] + ad_h;
  xsf = xsf > 0.f ? xsf : SLOPE * xsf;
  float evs = __expf(xsf);
  __half2 hself = Hf2[(size_t)node * 64 + lane];
  float accx = __low2float(hself) * evs;
  float accy = __high2float(hself) * evs;
  float sm = (el == 0) ? evs : 0.f;
  for (int ch = beg; ch < end; ch += 16) {
    int cnt = end - ch;
    int sv = node; float ev = 0.f;
    if (el < cnt) {
      sv = ssrc[ch + el];
      float x = alS[sv * 4 + hh] + ad_h;
      x = x > 0.f ? x : SLOPE * x;
      ev = __expf(x);
      sm += ev;
    }
    int sarr[16]; float av[16];
#pragma unroll
    for (int e = 0; e < 16; ++e) {
      sarr[e] = __shfl(sv, e, 64);
      av[e]   = __shfl(ev, hh * 16 + e, 64);
    }
    __half2 hv[16];
#pragma unroll
    for (int e = 0; e < 16; ++e)
      hv[e] = Hf2[(size_t)sarr[e] * 64 + lane];
#pragma unroll
    for (int e = 0; e < 16; ++e) {
      accx = fmaf(__low2float(hv[e]),  av[e], accx);
      accy = fmaf(__high2float(hv[e]), av[e], accy);
    }
  }
#pragma unroll
  for (int off = 8; off >= 1; off >>= 1) sm += __shfl_xor(sm, off, 64);
  float inv = 1.0f / sm;
  float vx = accx * inv + bias[2 * lane];
  float vy = accy * inv + bias[2 * lane + 1];
  vx = vx > 0.f ? vx : expm1f(vx);
  vy = vy > 0.f ? vy : expm1f(vy);
  outf[(size_t)node * 64 + lane] = __floats2half2_rn(vx, vy);
}

// ============ fused softmax + aggregation, H=1 (F=32): 16 lanes/node ============
__global__ void gat_agg_h1(const int* __restrict__ rp, const int* __restrict__ ssrc,
                           const __half2* __restrict__ Hf2, const float* __restrict__ alS,
                           const float* __restrict__ alD, const float* __restrict__ bias,
                           __half2* __restrict__ outf) {
  int node = (blockIdx.x * 256 + threadIdx.x) >> 4;
  int lane = threadIdx.x & 15;
  if (node >= NN) return;
  int beg = rp[node], end = rp[node + 1];
  float ad = alD[node];
  float xsf = alS[node] + ad;
  xsf = xsf > 0.f ? xsf : SLOPE * xsf;
  float evs = __expf(xsf);
  __half2 hself = Hf2[(size_t)node * 16 + lane];
  float accx = __low2float(hself) * evs;
  float accy = __high2float(hself) * evs;
  float sm = (lane == 0) ? evs : 0.f;
  for (int ch = beg; ch < end; ch += 16) {
    int cnt = end - ch;
    int sv = node; float ev = 0.f;
    if (lane < cnt) {
      sv = ssrc[ch + lane];
      float x = alS[sv] + ad;
      x = x > 0.f ? x : SLOPE * x;
      ev = __expf(x);
      sm += ev;
    }
    int sarr[16]; float av[16];
#pragma unroll
    for (int e = 0; e < 16; ++e) {
      sarr[e] = __shfl(sv, e, 16);
      av[e]   = __shfl(ev, e, 16);
    }
    __half2 hv[16];
#pragma unroll
    for (int e = 0; e < 16; ++e) hv[e] = Hf2[(size_t)sarr[e] * 16 + lane];
#pragma unroll
    for (int e = 0; e < 16; ++e) {
      accx = fmaf(__low2float(hv[e]),  av[e], accx);
      accy = fmaf(__high2float(hv[e]), av[e], accy);
    }
  }
#pragma unroll
  for (int off = 8; off >= 1; off >>= 1) sm += __shfl_xor(sm, off, 16);
  float inv = 1.0f / sm;
  float vx = accx * inv + bias[2 * lane];
  float vy = accy * inv + bias[2 * lane + 1];
  vx = vx > 0.f ? vx : expm1f(vx);
  vy = vy > 0.f ? vy : expm1f(vy);
  outf[(size_t)node * 16 + lane] = __floats2half2_rn(vx, vy);
}

// ======================= pool (sorted batch, fp16 feat) + heads =======================
__device__ __forceinline__ int lb_batch(const int* __restrict__ b, int val) {
  int lo = 0, hi = NN;
  while (lo < hi) { int mid = (lo + hi) >> 1; if (b[mid] < val) lo = mid + 1; else hi = mid; }
  return lo;
}

__global__ void pool_kernel(const __half2* __restrict__ feat, const int* __restrict__ batch,
                            float* __restrict__ pooled) {
  int g = blockIdx.x;
  int start = lb_batch(batch, g), end = lb_batch(batch, g + 1);
  int cp = threadIdx.x & 15, sub = threadIdx.x >> 4;   // 16 ch-pairs, 16 subgroups
  float ax = 0.f, ay = 0.f;
  for (int n = start + sub; n < end; n += 16) {
    __half2 v = feat[(size_t)n * 16 + cp];
    ax += __low2float(v);
    ay += __high2float(v);
  }
  __shared__ float red[16][32];
  red[sub][2 * cp] = ax;
  red[sub][2 * cp + 1] = ay;
  __syncthreads();
  if (threadIdx.x < 32) {
    float s = 0.f;
#pragma unroll
    for (int i = 0; i < 16; ++i) s += red[i][threadIdx.x];
    pooled[g * 32 + threadIdx.x] = s / fmaxf((float)(end - start), 1.0f);
  }
}

__global__ void head_kernel(const float* __restrict__ pooled,
                            const float* __restrict__ Wmu, const float* __restrict__ bmu,
                            const float* __restrict__ Wlv, const float* __restrict__ blv,
                            float* __restrict__ out) {
  int idx = blockIdx.x * 256 + threadIdx.x;
  if (idx >= NG * NLAT) return;
  int g = idx / NLAT, l = idx % NLAT;
  float mu = bmu[l], lv = blv[l];
#pragma unroll
  for (int k = 0; k < 32; ++k) {
    float p = pooled[g * 32 + k];
    mu = fmaf(p, Wmu[k * NLAT + l], mu);
    lv = fmaf(p, Wlv[k * NLAT + l], lv);
  }
  out[g * NLAT + l] = mu;
  out[NG * NLAT + g * NLAT + l] = lv;
}

extern "C" void kernel_launch(void* const* d_in, const int* in_sizes, int n_in,
                              void* d_out, int out_size, void* d_ws, size_t ws_size,
                              hipStream_t stream) {
  const float* x     = (const float*)d_in[0];
  const float* W1    = (const float*)d_in[1];
  const float* as1   = (const float*)d_in[2];
  const float* ad1   = (const float*)d_in[3];
  const float* b1    = (const float*)d_in[4];
  const float* W2    = (const float*)d_in[5];
  const float* as2   = (const float*)d_in[6];
  const float* ad2   = (const float*)d_in[7];
  const float* b2    = (const float*)d_in[8];
  const float* W3    = (const float*)d_in[9];
  const float* as3   = (const float*)d_in[10];
  const float* ad3   = (const float*)d_in[11];
  const float* b3    = (const float*)d_in[12];
  const float* Wmu   = (const float*)d_in[13];
  const float* bmu   = (const float*)d_in[14];
  const float* Wlv   = (const float*)d_in[15];
  const float* blv   = (const float*)d_in[16];
  const int*   ei    = (const int*)d_in[17];
  const int*   batch = (const int*)d_in[18];
  float* out = (float*)d_out;

  _Float16* A   = (_Float16*)d_ws;                  // [N,128] fp16 h (gemm out)
  _Float16* Bh  = A + (size_t)NN * 128;             // [N,128] fp16 features (agg out / gemm in)
  float* alS    = (float*)(Bh + (size_t)NN * 128);  // [N,4]
  float* alD    = alS + (size_t)NN * 4;             // [N,4]
  float* pooled = alD + (size_t)NN * 4;             // [G,32]
  _Float16* WT1 = (_Float16*)(pooled + (size_t)NG * 32);  // [128*128]
  _Float16* WT2 = WT1 + 16384;                      // [128*128]
  _Float16* WT3 = WT2 + 16384;                      // [32*128]
  int* rp       = (int*)(WT3 + 4096);               // [N+1]
  int* gcur     = rp + NN + 1;                      // [256]
  int* bbase    = gcur + 256;                       // [256]
  unsigned* gbuf = (unsigned*)(bbase + 256);        // [NBK*BCAP]
  int* ssrc     = (int*)(gbuf + (size_t)NBK * BCAP);// [NE]

  dim3 blk(256);

  // ---------------- CSR build + fp16 prep ----------------
  hipMemsetAsync(gcur, 0, 256 * sizeof(int), stream);
  p1_bucket<<<NB1, blk, 0, stream>>>(ei, gcur, gbuf);
  scan_buckets<<<1, blk, 0, stream>>>(gcur, bbase, rp);
  p2_sort<<<NBK, blk, 0, stream>>>(gbuf, gcur, bbase, rp, ssrc);
  wcast<<<288, 128, 0, stream>>>(W1, W2, W3, WT1, WT2, WT3);
  xcast<<<(NN * 16 + 255) / 256, blk, 0, stream>>>(x, Bh);   // x -> Bh fp16

  const int GB = (NN + 63) / 64;
  // ---------------- layer 1 ----------------
  gemm_mfma<128><<<GB, blk, 0, stream>>>(Bh, WT1, as1, ad1, A, alS, alD);
  gat_agg_h4<<<(NN * 64) / 256, blk, 0, stream>>>(rp, ssrc, (const __half2*)A, alS, alD, b1, (__half2*)Bh);
  // ---------------- layer 2 ----------------
  gemm_mfma<128><<<GB, blk, 0, stream>>>(Bh, WT2, as2, ad2, A, alS, alD);
  gat_agg_h4<<<(NN * 64) / 256, blk, 0, stream>>>(rp, ssrc, (const __half2*)A, alS, alD, b2, (__half2*)Bh);
  // ---------------- layer 3 ----------------
  gemm_mfma<32><<<GB, blk, 0, stream>>>(Bh, WT3, as3, ad3, A, alS, alD);
  gat_agg_h1<<<(NN * 16) / 256, blk, 0, stream>>>(rp, ssrc, (const __half2*)A, alS, alD, b3, (__half2*)Bh);

  // ---------------- pool + heads ----------------
  pool_kernel<<<NG, blk, 0, stream>>>((const __half2*)Bh, batch, pooled);
  head_kernel<<<(NG * NLAT + 255) / 256, blk, 0, stream>>>(pooled, Wmu, bmu, Wlv, blv, out);
}